// Round 3
// baseline (6392.606 us; speedup 1.0000x reference)
//
#include <hip/hip_runtime.h>
#include <math.h>

// ---------------------------------------------------------------------------
// CAMIL forward on MI355X, fp32 throughout (round 3: resubmit of round-2
// robustness build; GPU was unavailable last round).
constexpr int NTOK = 20000;   // N
constexpr int DIM  = 1024;    // D
constexpr int NEDGE= 320000;  // E
constexpr int NH   = 8;       // heads
constexpr int DH   = 64;      // head dim
constexpr int NLM  = 256;     // landmarks M
constexpr int PADF = 224;     // front pad  (M - N%M)
constexpr int NPD  = 20224;   // N + pad
constexpr int LGRP = 79;      // NPD / NLM
constexpr int PITERS = 6;

__device__ __forceinline__ float warpSum(float v){
  #pragma unroll
  for (int o = 32; o; o >>= 1) v += __shfl_xor(v, o);
  return v;
}
__device__ __forceinline__ float warpMax(float v){
  #pragma unroll
  for (int o = 32; o; o >>= 1) v = fmaxf(v, __shfl_xor(v, o));
  return v;
}

__global__ void zero_kernel(float* __restrict__ p, int n)
{
  int i = blockIdx.x * 256 + threadIdx.x;
  if (i < n) p[i] = 0.f;
}

// ---------------------------------------------------------------------------
// QKV GEMM: xp[NPD,1024] @ qkv_w[1024,1536] -> Q/K/V in [h][row][dh] layout.
// xp rows < PADF are zeros (front pad); no bias so those outputs are 0.
// Q scaled by DH^-0.5 = 0.125 here.
__global__ __launch_bounds__(256) void gemm_qkv_kernel(
    const float* __restrict__ bag, const float* __restrict__ Bw,
    float* __restrict__ Q, float* __restrict__ K, float* __restrict__ V)
{
  __shared__ float As[16][132];
  __shared__ float Bs[16][132];
  const int tid = threadIdx.x;
  const int tx = tid & 15, ty = tid >> 4;
  const int bm = blockIdx.y * 128, bn = blockIdx.x * 128;
  float acc[8][8] = {};
  for (int k0 = 0; k0 < 1024; k0 += 16) {
    float ra[8], rb[8];
    #pragma unroll
    for (int i = 0; i < 8; ++i) {
      int e = tid + 256 * i;
      int r = bm + (e >> 4);
      int c = k0 + (e & 15);
      ra[i] = (r >= PADF) ? bag[(size_t)(r - PADF) * 1024 + c] : 0.f;
      rb[i] = Bw[(size_t)(k0 + (e >> 7)) * 1536 + bn + (e & 127)];
    }
    __syncthreads();
    #pragma unroll
    for (int i = 0; i < 8; ++i) {
      int e = tid + 256 * i;
      As[e & 15][e >> 4]  = ra[i];
      Bs[e >> 7][e & 127] = rb[i];
    }
    __syncthreads();
    #pragma unroll
    for (int k = 0; k < 16; ++k) {
      float4 a0 = *(const float4*)&As[k][ty*4];
      float4 a1 = *(const float4*)&As[k][64 + ty*4];
      float4 b0 = *(const float4*)&Bs[k][tx*4];
      float4 b1 = *(const float4*)&Bs[k][64 + tx*4];
      float av[8] = {a0.x,a0.y,a0.z,a0.w,a1.x,a1.y,a1.z,a1.w};
      float bv[8] = {b0.x,b0.y,b0.z,b0.w,b1.x,b1.y,b1.z,b1.w};
      #pragma unroll
      for (int i = 0; i < 8; ++i)
        #pragma unroll
        for (int j = 0; j < 8; ++j)
          acc[i][j] += av[i] * bv[j];
    }
  }
  const int which = bn >> 9;
  float* dst = (which == 0) ? Q : (which == 1) ? K : V;
  const float scale = (which == 0) ? 0.125f : 1.f;
  #pragma unroll
  for (int i = 0; i < 8; ++i) {
    int r = bm + ((i < 4) ? (ty*4 + i) : (64 + ty*4 + (i - 4)));
    #pragma unroll
    for (int jh = 0; jh < 2; ++jh) {
      int col = bn + jh*64 + tx*4;
      int h  = (col & 511) >> 6;
      int dh = col & 63;
      float4 v;
      v.x = acc[i][jh*4+0] * scale;
      v.y = acc[i][jh*4+1] * scale;
      v.z = acc[i][jh*4+2] * scale;
      v.w = acc[i][jh*4+3] * scale;
      *(float4*)&dst[((size_t)h * NPD + r) * 64 + dh] = v;
    }
  }
}

// ---------------------------------------------------------------------------
// Generic fp32 GEMM: C[M,N] = A[M,K] @ B[K,N] (+bias[N]) (+add[M,N]).
__global__ __launch_bounds__(256) void gemm_f32_kernel(
    const float* __restrict__ A, const float* __restrict__ B,
    const float* __restrict__ bias, const float* __restrict__ add,
    float* __restrict__ C, int Mrows, int Ncols, int Kdim)
{
  __shared__ float As[16][132];
  __shared__ float Bs[16][132];
  const int tid = threadIdx.x;
  const int tx = tid & 15, ty = tid >> 4;
  const int bm = blockIdx.y * 128, bn = blockIdx.x * 128;
  float acc[8][8] = {};
  for (int k0 = 0; k0 < Kdim; k0 += 16) {
    float ra[8], rb[8];
    #pragma unroll
    for (int i = 0; i < 8; ++i) {
      int e = tid + 256 * i;
      int r = bm + (e >> 4);
      ra[i] = (r < Mrows) ? A[(size_t)r * Kdim + k0 + (e & 15)] : 0.f;
      rb[i] = B[(size_t)(k0 + (e >> 7)) * Ncols + bn + (e & 127)];
    }
    __syncthreads();
    #pragma unroll
    for (int i = 0; i < 8; ++i) {
      int e = tid + 256 * i;
      As[e & 15][e >> 4]  = ra[i];
      Bs[e >> 7][e & 127] = rb[i];
    }
    __syncthreads();
    #pragma unroll
    for (int k = 0; k < 16; ++k) {
      float4 a0 = *(const float4*)&As[k][ty*4];
      float4 a1 = *(const float4*)&As[k][64 + ty*4];
      float4 b0 = *(const float4*)&Bs[k][tx*4];
      float4 b1 = *(const float4*)&Bs[k][64 + tx*4];
      float av[8] = {a0.x,a0.y,a0.z,a0.w,a1.x,a1.y,a1.z,a1.w};
      float bv[8] = {b0.x,b0.y,b0.z,b0.w,b1.x,b1.y,b1.z,b1.w};
      #pragma unroll
      for (int i = 0; i < 8; ++i)
        #pragma unroll
        for (int j = 0; j < 8; ++j)
          acc[i][j] += av[i] * bv[j];
    }
  }
  #pragma unroll
  for (int i = 0; i < 8; ++i) {
    int r = bm + ((i < 4) ? (ty*4 + i) : (64 + ty*4 + (i - 4)));
    if (r >= Mrows) continue;
    #pragma unroll
    for (int jh = 0; jh < 2; ++jh) {
      int c0 = bn + jh*64 + tx*4;
      float4 v;
      v.x = acc[i][jh*4+0]; v.y = acc[i][jh*4+1];
      v.z = acc[i][jh*4+2]; v.w = acc[i][jh*4+3];
      if (bias) {
        float4 bb = *(const float4*)&bias[c0];
        v.x += bb.x; v.y += bb.y; v.z += bb.z; v.w += bb.w;
      }
      if (add) {
        float4 ad = *(const float4*)&add[(size_t)r * Ncols + c0];
        v.x += ad.x; v.y += ad.y; v.z += ad.z; v.w += ad.w;
      }
      *(float4*)&C[(size_t)r * Ncols + c0] = v;
    }
  }
}

// ---------------------------------------------------------------------------
// Batched-per-head 64x64-tile GEMM, with optional (dval*I - B) fold + scale.
__global__ __launch_bounds__(256) void bgemm64_kernel(
    const float* __restrict__ A, const float* __restrict__ B, float* __restrict__ C,
    int Msub, int Nsub, int Ksub, float dval, int useDiag, float scale)
{
  const int h = blockIdx.z;
  const float* Ah = A + (size_t)h * Msub * Ksub;
  const float* Bh = B + (size_t)h * Ksub * Nsub;
  float* Ch = C + (size_t)h * Msub * Nsub;
  __shared__ float As[16][68];
  __shared__ float Bs[16][64];
  const int tid = threadIdx.x, tx = tid & 15, ty = tid >> 4;
  const int bm = blockIdx.y * 64, bn = blockIdx.x * 64;
  float acc[4][4] = {};
  for (int k0 = 0; k0 < Ksub; k0 += 16) {
    float ra[4], rb[4];
    #pragma unroll
    for (int i = 0; i < 4; ++i) {
      int e = tid + 256 * i;
      ra[i] = Ah[(size_t)(bm + (e >> 4)) * Ksub + k0 + (e & 15)];
      int brow = k0 + (e >> 6), bcol = bn + (e & 63);
      float bv = Bh[(size_t)brow * Nsub + bcol];
      if (useDiag) bv = ((brow == bcol) ? dval : 0.f) - bv;
      rb[i] = bv;
    }
    __syncthreads();
    #pragma unroll
    for (int i = 0; i < 4; ++i) {
      int e = tid + 256 * i;
      As[e & 15][e >> 4] = ra[i];
      Bs[e >> 6][e & 63] = rb[i];
    }
    __syncthreads();
    #pragma unroll
    for (int k = 0; k < 16; ++k) {
      float4 a = *(const float4*)&As[k][ty*4];
      float4 b = *(const float4*)&Bs[k][tx*4];
      float av[4] = {a.x,a.y,a.z,a.w};
      float bv[4] = {b.x,b.y,b.z,b.w};
      #pragma unroll
      for (int i = 0; i < 4; ++i)
        #pragma unroll
        for (int j = 0; j < 4; ++j)
          acc[i][j] += av[i] * bv[j];
    }
  }
  #pragma unroll
  for (int i = 0; i < 4; ++i) {
    float4 v = {acc[i][0]*scale, acc[i][1]*scale, acc[i][2]*scale, acc[i][3]*scale};
    *(float4*)&Ch[(size_t)(bm + ty*4 + i) * Nsub + bn + tx*4] = v;
  }
}

// ---------------------------------------------------------------------------
__global__ __launch_bounds__(64) void landmark_kernel(
    const float* __restrict__ src, float* __restrict__ dst)
{
  int m = blockIdx.x, h = blockIdx.y, d = threadIdx.x;
  const float* p = src + ((size_t)h * NPD + (size_t)m * LGRP) * 64 + d;
  float acc = 0.f;
  for (int j = 0; j < LGRP; ++j) acc += p[(size_t)j * 64];
  dst[((size_t)h * NLM + m) * 64 + d] = acc / (float)LGRP;
}

// ---------------------------------------------------------------------------
__global__ __launch_bounds__(256) void a2_kernel(
    const float* __restrict__ qlm, const float* __restrict__ klm, float* __restrict__ a2)
{
  int i = blockIdx.x, h = blockIdx.y, t = threadIdx.x;
  int w = t >> 6, lane = t & 63;
  __shared__ float qs[64];
  __shared__ float wr[4], wr2[4];
  if (t < 64) qs[t] = qlm[((size_t)h * NLM + i) * 64 + t];
  __syncthreads();
  const float* kr = klm + ((size_t)h * NLM + t) * 64;
  float s = 0.f;
  #pragma unroll
  for (int d2 = 0; d2 < 64; d2 += 4) {
    float4 kv = *(const float4*)(kr + d2);
    s += qs[d2]*kv.x + qs[d2+1]*kv.y + qs[d2+2]*kv.z + qs[d2+3]*kv.w;
  }
  float mx = warpMax(s);
  if (lane == 0) wr[w] = mx;
  __syncthreads();
  mx = fmaxf(fmaxf(wr[0], wr[1]), fmaxf(wr[2], wr[3]));
  float e = expf(s - mx);
  float sm = warpSum(e);
  if (lane == 0) wr2[w] = sm;
  __syncthreads();
  sm = wr2[0] + wr2[1] + wr2[2] + wr2[3];
  a2[((size_t)h * NLM + i) * NLM + t] = e / sm;
}

// ---------------------------------------------------------------------------
__global__ __launch_bounds__(256) void rowcolmax_kernel(
    const float* __restrict__ a2, float* __restrict__ scal)
{
  int h = blockIdx.x >> 1, mode = blockIdx.x & 1, t = threadIdx.x;
  int w = t >> 6, lane = t & 63;
  float sum = 0.f;
  if (mode == 0) {
    const float* p = a2 + ((size_t)h * NLM + t) * NLM;
    for (int j = 0; j < NLM; ++j) sum += p[j];
  } else {
    const float* p = a2 + (size_t)h * NLM * NLM + t;
    for (int i = 0; i < NLM; ++i) sum += p[(size_t)i * NLM];
  }
  float mx = warpMax(sum);
  __shared__ float wr[4];
  if (lane == 0) wr[w] = mx;
  __syncthreads();
  if (t == 0) {
    float m2 = fmaxf(fmaxf(wr[0], wr[1]), fmaxf(wr[2], wr[3]));
    atomicMax((int*)&scal[mode], __float_as_int(m2));
  }
}

__global__ __launch_bounds__(256) void initz_kernel(
    const float* __restrict__ a2, const float* __restrict__ scal, float* __restrict__ z)
{
  int i = blockIdx.x, h = blockIdx.y, t = threadIdx.x;
  float inv = 1.f / (scal[0] * scal[1]);
  z[((size_t)h * NLM + i) * NLM + t] = a2[((size_t)h * NLM + t) * NLM + i] * inv;
}

// ---------------------------------------------------------------------------
__global__ __launch_bounds__(256) void flash_a3v_kernel(
    const float* __restrict__ qlm, const float* __restrict__ K,
    const float* __restrict__ V, float* __restrict__ AV)
{
  int m = blockIdx.x, h = blockIdx.y, t = threadIdx.x;
  __shared__ float qs[64];
  __shared__ float red[256];
  __shared__ float ps[256];
  if (t < 64) qs[t] = qlm[((size_t)h * NLM + m) * 64 + t];
  __syncthreads();
  const float* Kh = K + (size_t)h * NPD * 64;
  const float* Vh = V + (size_t)h * NPD * 64;
  float mloc = -INFINITY;
  for (int tile = 0; tile < NPD / 256; ++tile) {
    const float* kr = Kh + ((size_t)tile * 256 + t) * 64;
    float s = 0.f;
    #pragma unroll
    for (int d2 = 0; d2 < 64; d2 += 4) {
      float4 kv = *(const float4*)(kr + d2);
      s += qs[d2]*kv.x + qs[d2+1]*kv.y + qs[d2+2]*kv.z + qs[d2+3]*kv.w;
    }
    mloc = fmaxf(mloc, s);
  }
  red[t] = mloc; __syncthreads();
  for (int s2 = 128; s2 > 0; s2 >>= 1) {
    if (t < s2) red[t] = fmaxf(red[t], red[t + s2]);
    __syncthreads();
  }
  const float MX = red[0];
  __syncthreads();
  int sub = t >> 6, d = t & 63;
  float acc = 0.f, lsum = 0.f;
  for (int tile = 0; tile < NPD / 256; ++tile) {
    const float* kr = Kh + ((size_t)tile * 256 + t) * 64;
    float s = 0.f;
    #pragma unroll
    for (int d2 = 0; d2 < 64; d2 += 4) {
      float4 kv = *(const float4*)(kr + d2);
      s += qs[d2]*kv.x + qs[d2+1]*kv.y + qs[d2+2]*kv.z + qs[d2+3]*kv.w;
    }
    float p = expf(s - MX);
    lsum += p;
    ps[t] = p;
    __syncthreads();
    const float* vr = Vh + ((size_t)tile * 256 + sub * 64) * 64 + d;
    #pragma unroll 8
    for (int jj = 0; jj < 64; ++jj)
      acc += ps[sub * 64 + jj] * vr[(size_t)jj * 64];
    __syncthreads();
  }
  red[t] = lsum; __syncthreads();
  for (int s2 = 128; s2 > 0; s2 >>= 1) {
    if (t < s2) red[t] += red[t + s2];
    __syncthreads();
  }
  const float LS = red[0];
  __syncthreads();
  red[t] = acc; __syncthreads();
  if (t < 64) {
    float r = red[t] + red[t + 64] + red[t + 128] + red[t + 192];
    AV[((size_t)h * NLM + m) * 64 + t] = r / LS;
  }
}

// ---------------------------------------------------------------------------
__global__ __launch_bounds__(256) void a1_fused_kernel(
    const float* __restrict__ Q, const float* __restrict__ klm,
    const float* __restrict__ W, float* __restrict__ O1)
{
  int h = blockIdx.y;
  int rb = blockIdx.x * 8;
  int t = threadIdx.x;
  int w = t >> 6, lane = t & 63;
  __shared__ float qs[8][64];
  __shared__ float ps[8][256];
  __shared__ float Wl[128 * 64];
  for (int e = t; e < 8 * 64; e += 256) {
    int r = e >> 6, d2 = e & 63;
    qs[r][d2] = Q[((size_t)h * NPD + PADF + rb + r) * 64 + d2];
  }
  __syncthreads();
  const float* kr = klm + ((size_t)h * NLM + t) * 64;
  float s[8] = {};
  #pragma unroll
  for (int d2 = 0; d2 < 64; d2 += 4) {
    float4 kv = *(const float4*)(kr + d2);
    #pragma unroll
    for (int r = 0; r < 8; ++r)
      s[r] += qs[r][d2]*kv.x + qs[r][d2+1]*kv.y + qs[r][d2+2]*kv.z + qs[r][d2+3]*kv.w;
  }
  #pragma unroll
  for (int r = 0; r < 8; ++r) ps[r][t] = s[r];
  __syncthreads();
  for (int r = w; r < 8; r += 4) {
    float v0 = ps[r][lane], v1 = ps[r][lane+64], v2 = ps[r][lane+128], v3 = ps[r][lane+192];
    float mx = warpMax(fmaxf(fmaxf(v0, v1), fmaxf(v2, v3)));
    float e0 = expf(v0-mx), e1 = expf(v1-mx), e2 = expf(v2-mx), e3 = expf(v3-mx);
    float inv = 1.f / warpSum(e0 + e1 + e2 + e3);
    ps[r][lane] = e0*inv; ps[r][lane+64] = e1*inv; ps[r][lane+128] = e2*inv; ps[r][lane+192] = e3*inv;
  }
  const float* Wh = W + (size_t)h * NLM * 64;
  int r0 = t >> 6, d = t & 63;
  float accA = 0.f, accB = 0.f;
  for (int half = 0; half < 2; ++half) {
    __syncthreads();
    for (int e = t; e < 2048; e += 256)
      ((float4*)Wl)[e] = ((const float4*)(Wh + (size_t)half * 8192))[e];
    __syncthreads();
    #pragma unroll 16
    for (int j = 0; j < 128; ++j) {
      float wv = Wl[j * 64 + d];
      accA += ps[r0][half*128 + j] * wv;
      accB += ps[r0 + 4][half*128 + j] * wv;
    }
  }
  O1[((size_t)rb + r0) * 512 + h*64 + d] = accA;
  O1[((size_t)rb + r0 + 4) * 512 + h*64 + d] = accB;
}

// ---------------------------------------------------------------------------
__global__ __launch_bounds__(512) void conv_res_kernel(
    const float* __restrict__ V, const float* __restrict__ rw, float* __restrict__ O1)
{
  int t = threadIdx.x;
  int h = t >> 6, d = t & 63;
  int i = PADF + blockIdx.x;
  __shared__ float wsm[264];
  if (t < 264) wsm[t] = rw[t];
  __syncthreads();
  const float* vp = V + ((size_t)h * NPD + i - 16) * 64 + d;
  float acc = 0.f;
  #pragma unroll
  for (int k = 0; k < 33; ++k) {
    int row = i - 16 + k;
    float vv = (row < NPD) ? vp[(size_t)k * 64] : 0.f;
    acc += wsm[h*33 + k] * vv;
  }
  O1[(size_t)blockIdx.x * 512 + t] += acc;
}

// ---------------------------------------------------------------------------
__global__ __launch_bounds__(256) void edge_kernel(
    const float* __restrict__ Q2, const float* __restrict__ K2,
    const int* __restrict__ rows, const int* __restrict__ cols,
    const float* __restrict__ vals, float* __restrict__ A_raw)
{
  int e = blockIdx.x * 4 + (threadIdx.x >> 6);
  int lane = threadIdx.x & 63;
  int r = rows[e], c = cols[e];
  float4 q = *(const float4*)&Q2[(size_t)r * 256 + lane * 4];
  float4 k = *(const float4*)&K2[(size_t)c * 256 + lane * 4];
  float s = q.x*k.x + q.y*k.y + q.z*k.z + q.w*k.w;
  s = warpSum(s);
  if (lane == 0) atomicAdd(&A_raw[r], s * 0.0625f * vals[e]);
}

__global__ __launch_bounds__(1024) void softmax_vec_kernel(
    const float* __restrict__ x, float* __restrict__ y)
{
  __shared__ float red[1024];
  int t = threadIdx.x;
  float mx = -INFINITY;
  for (int i = t; i < NTOK; i += 1024) mx = fmaxf(mx, x[i]);
  red[t] = mx; __syncthreads();
  for (int s = 512; s > 0; s >>= 1) { if (t < s) red[t] = fmaxf(red[t], red[t+s]); __syncthreads(); }
  mx = red[0]; __syncthreads();
  float sm = 0.f;
  for (int i = t; i < NTOK; i += 1024) sm += expf(x[i] - mx);
  red[t] = sm; __syncthreads();
  for (int s = 512; s > 0; s >>= 1) { if (t < s) red[t] += red[t+s]; __syncthreads(); }
  sm = red[0];
  float inv = 1.f / sm;
  for (int i = t; i < NTOK; i += 1024) y[i] = expf(x[i] - mx) * inv;
}

__global__ __launch_bounds__(256) void xo_kernel(
    const float* __restrict__ alpha, float* __restrict__ VAL, const float* __restrict__ EO)
{
  int row = blockIdx.x, t = threadIdx.x;
  float a = alpha[row];
  size_t base = (size_t)row * 1024 + t * 4;
  float4 v = *(const float4*)&VAL[base];
  float4 e = *(const float4*)&EO[base];
  float xv[4] = {v.x, v.y, v.z, v.w};
  float ev[4] = {e.x, e.y, e.z, e.w};
  float xo[4];
  #pragma unroll
  for (int i = 0; i < 4; ++i) {
    float xl = a * xv[i];
    float sg = 1.f / (1.f + expf(xl));
    float sw = sg * sg;
    xo[i] = xl * 2.f * sw + 2.f * ev[i] * (1.f - sw);
  }
  float4 r = {xo[0], xo[1], xo[2], xo[3]};
  *(float4*)&VAL[base] = r;
}

__global__ void ones_kernel(float* __restrict__ p, int n)
{
  int i = blockIdx.x * 256 + threadIdx.x;
  if (i < n) p[i] = 1.f;
}

__global__ __launch_bounds__(256) void pooled_kernel(
    const float* __restrict__ XO, float* __restrict__ pool)
{
  int c = blockIdx.x * 256 + threadIdx.x;
  int r0 = blockIdx.y * 500;
  float acc = 0.f;
  for (int r = r0; r < r0 + 500; ++r) acc += XO[(size_t)r * DIM + c];
  atomicAdd(&pool[c], acc);
}

__global__ __launch_bounds__(128) void final_kernel(
    const float* __restrict__ pool, const float* __restrict__ fcw,
    const float* __restrict__ fcb, const float* __restrict__ fcb2,
    float* __restrict__ out)
{
  int t = threadIdx.x, c = t >> 6, lane = t & 63;
  float acc = 0.f;
  for (int d = lane; d < DIM; d += 64)
    acc += pool[d] * (1.f / (float)NTOK) * fcw[d * 2 + c];
  acc = warpSum(acc);
  if (lane == 0) out[c] = acc + fcb[c] + fcb2[c];
}

// ---------------------------------------------------------------------------
extern "C" void kernel_launch(void* const* d_in, const int* in_sizes, int n_in,
                              void* d_out, int out_size, void* d_ws, size_t ws_size,
                              hipStream_t stream)
{
  float* out = (float*)d_out;

  // ---- workspace arena with aliasing (peak ~262 MB) ----
  constexpr size_t QKV_SZ = (size_t)NH * NPD * DH;   // 10,354,688 floats
  constexpr size_t O1_SZ  = (size_t)NTOK * 512;      // 10,240,000
  constexpr size_t EO_SZ  = (size_t)NTOK * DIM;      // 20,480,000
  float* w = (float*)d_ws;
  size_t o = 0;
  auto alloc = [&](size_t n) { float* p = w + o; o += (n + 3) & ~(size_t)3; return p; };
  float* Q    = alloc(QKV_SZ);
  float* K    = alloc(QKV_SZ);
  float* V    = alloc(QKV_SZ);     // VAL later aliases [V, V+EO_SZ) = V+O1 window
  float* O1   = alloc(O1_SZ);
  float* EO   = alloc(EO_SZ);
  float* QLM  = alloc((size_t)NH * NLM * DH);
  float* KLM  = alloc((size_t)NH * NLM * DH);
  float* A2   = alloc((size_t)NH * NLM * NLM);
  float* Z0   = alloc((size_t)NH * NLM * NLM);
  float* Z1   = alloc((size_t)NH * NLM * NLM);
  float* T1   = alloc((size_t)NH * NLM * NLM);
  float* T2   = alloc((size_t)NH * NLM * NLM);
  float* T3   = alloc((size_t)NH * NLM * NLM);
  float* AV   = alloc((size_t)NH * NLM * DH);
  float* WM   = alloc((size_t)NH * NLM * DH);
  float* ALPHA= alloc(NTOK);
  float* POOL = alloc(1024);
  float* SCAL = alloc(8);
  const size_t needed_bytes = o * sizeof(float);

  // Aliases (lifetimes: V dead after conv_res; O1 dead after EO gemm;
  // Q dead after a1_fused; K dead after flash_a3v — all before first use below)
  float* VAL = V;      // V+O1 window = 20,594,688 floats >= EO_SZ  OK
  float* Q2  = Q;      // [NTOK,256]
  float* K2  = K;

  // Fail cleanly (zeros) instead of faulting if environment differs from spec.
  if (n_in < 23 || ws_size < needed_bytes || out_size < 2 + NTOK + NTOK) {
    int grid = out_size > 0 ? (out_size + 255) / 256 : 1;
    zero_kernel<<<grid, 256, 0, stream>>>(out, out_size);
    return;
  }

  const float* bag  = (const float*)d_in[0];
  const float* adjv = (const float*)d_in[1];
  const float* qkvw = (const float*)d_in[2];
  const float* outw = (const float*)d_in[3];
  const float* outb = (const float*)d_in[4];
  const float* resw = (const float*)d_in[5];
  const float* wqw  = (const float*)d_in[6];
  const float* wqb  = (const float*)d_in[7];
  const float* wkw  = (const float*)d_in[8];
  const float* wkb  = (const float*)d_in[9];
  const float* wvw  = (const float*)d_in[10];
  const float* wvb  = (const float*)d_in[11];
  // d_in[12..17]: va/ua/wa — dead (k_alpha = softmax over singleton axis = 1.0)
  const float* fcw  = (const float*)d_in[18];
  const float* fcb  = (const float*)d_in[19];
  const float* fcb2 = (const float*)d_in[20];
  const int* arows  = (const int*)d_in[21];
  const int* acols  = (const int*)d_in[22];

  float* A_raw  = out + 2;
  float* kalpha = A_raw + NTOK;

  zero_kernel<<<(NTOK + 255) / 256, 256, 0, stream>>>(A_raw, NTOK);
  zero_kernel<<<4, 256, 0, stream>>>(POOL, 1024);
  zero_kernel<<<1, 256, 0, stream>>>(SCAL, 8);

  // --- Nystrom encoder ---
  gemm_qkv_kernel<<<dim3(1536/128, NPD/128), 256, 0, stream>>>(bag, qkvw, Q, K, V);
  landmark_kernel<<<dim3(NLM, NH), 64, 0, stream>>>(Q, QLM);
  landmark_kernel<<<dim3(NLM, NH), 64, 0, stream>>>(K, KLM);
  a2_kernel<<<dim3(NLM, NH), 256, 0, stream>>>(QLM, KLM, A2);
  rowcolmax_kernel<<<16, 256, 0, stream>>>(A2, SCAL);
  initz_kernel<<<dim3(NLM, NH), 256, 0, stream>>>(A2, SCAL, Z0);

  auto bgemm = [&](const float* Ab, const float* Bb, float* Cb,
                   int Ms, int Ns, int Ks, float dval, int useDiag, float scale) {
    bgemm64_kernel<<<dim3(Ns/64, Ms/64, NH), 256, 0, stream>>>(Ab, Bb, Cb, Ms, Ns, Ks, dval, useDiag, scale);
  };
  float* zc = Z0; float* zn = Z1;
  for (int it = 0; it < PITERS; ++it) {
    bgemm(A2, zc, T1, NLM, NLM, NLM, 0.f,  0, 1.f);    // T1 = X @ Z
    bgemm(T1, T1, T2, NLM, NLM, NLM, 7.f,  1, 1.f);    // T2 = T1 @ (7I - T1)
    bgemm(T1, T2, T3, NLM, NLM, NLM, 15.f, 1, 1.f);    // T3 = T1 @ (15I - T2)
    bgemm(zc, T3, zn, NLM, NLM, NLM, 13.f, 1, 0.25f);  // Z' = 0.25 Z @ (13I - T3)
    float* tmp = zc; zc = zn; zn = tmp;
  }
  flash_a3v_kernel<<<dim3(NLM, NH), 256, 0, stream>>>(QLM, K, V, AV);
  bgemm(zc, AV, WM, NLM, DH, NLM, 0.f, 0, 1.f);        // W = pinv(a2) @ (a3@v)
  a1_fused_kernel<<<dim3(NTOK/8, NH), 256, 0, stream>>>(Q, KLM, WM, O1);
  conv_res_kernel<<<NTOK, 512, 0, stream>>>(V, resw, O1);
  gemm_f32_kernel<<<dim3(DIM/128, (NTOK+127)/128), 256, 0, stream>>>(
      O1, outw, outb, bag, EO, NTOK, DIM, 512);        // eo = proj(O1)+bag
  // V and O1 are now dead -> their window is VAL from here on.

  // --- CustomAttention + NeighborAggregator ---
  gemm_f32_kernel<<<dim3(256/128, (NTOK+127)/128), 256, 0, stream>>>(
      EO, wqw, wqb, nullptr, Q2, NTOK, 256, DIM);
  gemm_f32_kernel<<<dim3(256/128, (NTOK+127)/128), 256, 0, stream>>>(
      EO, wkw, wkb, nullptr, K2, NTOK, 256, DIM);
  edge_kernel<<<NEDGE/4, 256, 0, stream>>>(Q2, K2, arows, acols, adjv, A_raw);
  softmax_vec_kernel<<<1, 1024, 0, stream>>>(A_raw, ALPHA);

  // --- value / gating / pooling ---
  gemm_f32_kernel<<<dim3(DIM/128, (NTOK+127)/128), 256, 0, stream>>>(
      bag, wvw, wvb, nullptr, VAL, NTOK, DIM, DIM);
  xo_kernel<<<NTOK, 256, 0, stream>>>(ALPHA, VAL, EO);
  ones_kernel<<<(NTOK+255)/256, 256, 0, stream>>>(kalpha, NTOK);
  pooled_kernel<<<dim3(4, 40), 256, 0, stream>>>(VAL, POOL);
  final_kernel<<<1, 128, 0, stream>>>(POOL, fcw, fcb, fcb2, out);
}

// Round 4
// 3747.987 us; speedup vs baseline: 1.7056x; 1.7056x over previous
//
#include <hip/hip_runtime.h>
#include <math.h>

// ---------------------------------------------------------------------------
// CAMIL forward on MI355X, fp32 throughout.
// Round 4: replace latency-bound flash_a3v (3030us, 47% of runtime) with a
// materialized-S^T GEMM pipeline (st_gemm -> smax1/2 -> pv split-K -> norm).
constexpr int NTOK = 20000;   // N
constexpr int DIM  = 1024;    // D
constexpr int NEDGE= 320000;  // E
constexpr int NH   = 8;       // heads
constexpr int DH   = 64;      // head dim
constexpr int NLM  = 256;     // landmarks M
constexpr int PADF = 224;     // front pad  (M - N%M)
constexpr int NPD  = 20224;   // N + pad
constexpr int LGRP = 79;      // NPD / NLM
constexpr int PITERS = 6;
constexpr int JSPL = 16;              // pv split-K chunks
constexpr int JLEN = NPD / JSPL;      // 1264 (= 79 * 16, exact)
constexpr int NCHK = 79;              // smax1 chunks (NPD / 256)

__device__ __forceinline__ float warpSum(float v){
  #pragma unroll
  for (int o = 32; o; o >>= 1) v += __shfl_xor(v, o);
  return v;
}
__device__ __forceinline__ float warpMax(float v){
  #pragma unroll
  for (int o = 32; o; o >>= 1) v = fmaxf(v, __shfl_xor(v, o));
  return v;
}

__global__ void zero_kernel(float* __restrict__ p, int n)
{
  int i = blockIdx.x * 256 + threadIdx.x;
  if (i < n) p[i] = 0.f;
}

// ---------------------------------------------------------------------------
// QKV GEMM: xp[NPD,1024] @ qkv_w[1024,1536] -> Q/K/V in [h][row][dh] layout.
// xp rows < PADF are zeros (front pad); no bias so those outputs are 0.
// Q scaled by DH^-0.5 = 0.125 here.
__global__ __launch_bounds__(256) void gemm_qkv_kernel(
    const float* __restrict__ bag, const float* __restrict__ Bw,
    float* __restrict__ Q, float* __restrict__ K, float* __restrict__ V)
{
  __shared__ float As[16][132];
  __shared__ float Bs[16][132];
  const int tid = threadIdx.x;
  const int tx = tid & 15, ty = tid >> 4;
  const int bm = blockIdx.y * 128, bn = blockIdx.x * 128;
  float acc[8][8] = {};
  for (int k0 = 0; k0 < 1024; k0 += 16) {
    float ra[8], rb[8];
    #pragma unroll
    for (int i = 0; i < 8; ++i) {
      int e = tid + 256 * i;
      int r = bm + (e >> 4);
      int c = k0 + (e & 15);
      ra[i] = (r >= PADF) ? bag[(size_t)(r - PADF) * 1024 + c] : 0.f;
      rb[i] = Bw[(size_t)(k0 + (e >> 7)) * 1536 + bn + (e & 127)];
    }
    __syncthreads();
    #pragma unroll
    for (int i = 0; i < 8; ++i) {
      int e = tid + 256 * i;
      As[e & 15][e >> 4]  = ra[i];
      Bs[e >> 7][e & 127] = rb[i];
    }
    __syncthreads();
    #pragma unroll
    for (int k = 0; k < 16; ++k) {
      float4 a0 = *(const float4*)&As[k][ty*4];
      float4 a1 = *(const float4*)&As[k][64 + ty*4];
      float4 b0 = *(const float4*)&Bs[k][tx*4];
      float4 b1 = *(const float4*)&Bs[k][64 + tx*4];
      float av[8] = {a0.x,a0.y,a0.z,a0.w,a1.x,a1.y,a1.z,a1.w};
      float bv[8] = {b0.x,b0.y,b0.z,b0.w,b1.x,b1.y,b1.z,b1.w};
      #pragma unroll
      for (int i = 0; i < 8; ++i)
        #pragma unroll
        for (int j = 0; j < 8; ++j)
          acc[i][j] += av[i] * bv[j];
    }
  }
  const int which = bn >> 9;
  float* dst = (which == 0) ? Q : (which == 1) ? K : V;
  const float scale = (which == 0) ? 0.125f : 1.f;
  #pragma unroll
  for (int i = 0; i < 8; ++i) {
    int r = bm + ((i < 4) ? (ty*4 + i) : (64 + ty*4 + (i - 4)));
    #pragma unroll
    for (int jh = 0; jh < 2; ++jh) {
      int col = bn + jh*64 + tx*4;
      int h  = (col & 511) >> 6;
      int dh = col & 63;
      float4 v;
      v.x = acc[i][jh*4+0] * scale;
      v.y = acc[i][jh*4+1] * scale;
      v.z = acc[i][jh*4+2] * scale;
      v.w = acc[i][jh*4+3] * scale;
      *(float4*)&dst[((size_t)h * NPD + r) * 64 + dh] = v;
    }
  }
}

// ---------------------------------------------------------------------------
// Generic fp32 GEMM: C[M,N] = A[M,K] @ B[K,N] (+bias[N]) (+add[M,N]).
__global__ __launch_bounds__(256) void gemm_f32_kernel(
    const float* __restrict__ A, const float* __restrict__ B,
    const float* __restrict__ bias, const float* __restrict__ add,
    float* __restrict__ C, int Mrows, int Ncols, int Kdim)
{
  __shared__ float As[16][132];
  __shared__ float Bs[16][132];
  const int tid = threadIdx.x;
  const int tx = tid & 15, ty = tid >> 4;
  const int bm = blockIdx.y * 128, bn = blockIdx.x * 128;
  float acc[8][8] = {};
  for (int k0 = 0; k0 < Kdim; k0 += 16) {
    float ra[8], rb[8];
    #pragma unroll
    for (int i = 0; i < 8; ++i) {
      int e = tid + 256 * i;
      int r = bm + (e >> 4);
      ra[i] = (r < Mrows) ? A[(size_t)r * Kdim + k0 + (e & 15)] : 0.f;
      rb[i] = B[(size_t)(k0 + (e >> 7)) * Ncols + bn + (e & 127)];
    }
    __syncthreads();
    #pragma unroll
    for (int i = 0; i < 8; ++i) {
      int e = tid + 256 * i;
      As[e & 15][e >> 4]  = ra[i];
      Bs[e >> 7][e & 127] = rb[i];
    }
    __syncthreads();
    #pragma unroll
    for (int k = 0; k < 16; ++k) {
      float4 a0 = *(const float4*)&As[k][ty*4];
      float4 a1 = *(const float4*)&As[k][64 + ty*4];
      float4 b0 = *(const float4*)&Bs[k][tx*4];
      float4 b1 = *(const float4*)&Bs[k][64 + tx*4];
      float av[8] = {a0.x,a0.y,a0.z,a0.w,a1.x,a1.y,a1.z,a1.w};
      float bv[8] = {b0.x,b0.y,b0.z,b0.w,b1.x,b1.y,b1.z,b1.w};
      #pragma unroll
      for (int i = 0; i < 8; ++i)
        #pragma unroll
        for (int j = 0; j < 8; ++j)
          acc[i][j] += av[i] * bv[j];
    }
  }
  #pragma unroll
  for (int i = 0; i < 8; ++i) {
    int r = bm + ((i < 4) ? (ty*4 + i) : (64 + ty*4 + (i - 4)));
    if (r >= Mrows) continue;
    #pragma unroll
    for (int jh = 0; jh < 2; ++jh) {
      int c0 = bn + jh*64 + tx*4;
      float4 v;
      v.x = acc[i][jh*4+0]; v.y = acc[i][jh*4+1];
      v.z = acc[i][jh*4+2]; v.w = acc[i][jh*4+3];
      if (bias) {
        float4 bb = *(const float4*)&bias[c0];
        v.x += bb.x; v.y += bb.y; v.z += bb.z; v.w += bb.w;
      }
      if (add) {
        float4 ad = *(const float4*)&add[(size_t)r * Ncols + c0];
        v.x += ad.x; v.y += ad.y; v.z += ad.z; v.w += ad.w;
      }
      *(float4*)&C[(size_t)r * Ncols + c0] = v;
    }
  }
}

// ---------------------------------------------------------------------------
// Batched-per-head 64x64-tile GEMM, with optional (dval*I - B) fold + scale.
__global__ __launch_bounds__(256) void bgemm64_kernel(
    const float* __restrict__ A, const float* __restrict__ B, float* __restrict__ C,
    int Msub, int Nsub, int Ksub, float dval, int useDiag, float scale)
{
  const int h = blockIdx.z;
  const float* Ah = A + (size_t)h * Msub * Ksub;
  const float* Bh = B + (size_t)h * Ksub * Nsub;
  float* Ch = C + (size_t)h * Msub * Nsub;
  __shared__ float As[16][68];
  __shared__ float Bs[16][64];
  const int tid = threadIdx.x, tx = tid & 15, ty = tid >> 4;
  const int bm = blockIdx.y * 64, bn = blockIdx.x * 64;
  float acc[4][4] = {};
  for (int k0 = 0; k0 < Ksub; k0 += 16) {
    float ra[4], rb[4];
    #pragma unroll
    for (int i = 0; i < 4; ++i) {
      int e = tid + 256 * i;
      ra[i] = Ah[(size_t)(bm + (e >> 4)) * Ksub + k0 + (e & 15)];
      int brow = k0 + (e >> 6), bcol = bn + (e & 63);
      float bv = Bh[(size_t)brow * Nsub + bcol];
      if (useDiag) bv = ((brow == bcol) ? dval : 0.f) - bv;
      rb[i] = bv;
    }
    __syncthreads();
    #pragma unroll
    for (int i = 0; i < 4; ++i) {
      int e = tid + 256 * i;
      As[e & 15][e >> 4] = ra[i];
      Bs[e >> 6][e & 63] = rb[i];
    }
    __syncthreads();
    #pragma unroll
    for (int k = 0; k < 16; ++k) {
      float4 a = *(const float4*)&As[k][ty*4];
      float4 b = *(const float4*)&Bs[k][tx*4];
      float av[4] = {a.x,a.y,a.z,a.w};
      float bv[4] = {b.x,b.y,b.z,b.w};
      #pragma unroll
      for (int i = 0; i < 4; ++i)
        #pragma unroll
        for (int j = 0; j < 4; ++j)
          acc[i][j] += av[i] * bv[j];
    }
  }
  #pragma unroll
  for (int i = 0; i < 4; ++i) {
    float4 v = {acc[i][0]*scale, acc[i][1]*scale, acc[i][2]*scale, acc[i][3]*scale};
    *(float4*)&Ch[(size_t)(bm + ty*4 + i) * Nsub + bn + tx*4] = v;
  }
}

// ---------------------------------------------------------------------------
__global__ __launch_bounds__(64) void landmark_kernel(
    const float* __restrict__ src, float* __restrict__ dst)
{
  int m = blockIdx.x, h = blockIdx.y, d = threadIdx.x;
  const float* p = src + ((size_t)h * NPD + (size_t)m * LGRP) * 64 + d;
  float acc = 0.f;
  for (int j = 0; j < LGRP; ++j) acc += p[(size_t)j * 64];
  dst[((size_t)h * NLM + m) * 64 + d] = acc / (float)LGRP;
}

// ---------------------------------------------------------------------------
__global__ __launch_bounds__(256) void a2_kernel(
    const float* __restrict__ qlm, const float* __restrict__ klm, float* __restrict__ a2)
{
  int i = blockIdx.x, h = blockIdx.y, t = threadIdx.x;
  int w = t >> 6, lane = t & 63;
  __shared__ float qs[64];
  __shared__ float wr[4], wr2[4];
  if (t < 64) qs[t] = qlm[((size_t)h * NLM + i) * 64 + t];
  __syncthreads();
  const float* kr = klm + ((size_t)h * NLM + t) * 64;
  float s = 0.f;
  #pragma unroll
  for (int d2 = 0; d2 < 64; d2 += 4) {
    float4 kv = *(const float4*)(kr + d2);
    s += qs[d2]*kv.x + qs[d2+1]*kv.y + qs[d2+2]*kv.z + qs[d2+3]*kv.w;
  }
  float mx = warpMax(s);
  if (lane == 0) wr[w] = mx;
  __syncthreads();
  mx = fmaxf(fmaxf(wr[0], wr[1]), fmaxf(wr[2], wr[3]));
  float e = expf(s - mx);
  float sm = warpSum(e);
  if (lane == 0) wr2[w] = sm;
  __syncthreads();
  sm = wr2[0] + wr2[1] + wr2[2] + wr2[3];
  a2[((size_t)h * NLM + i) * NLM + t] = e / sm;
}

// ---------------------------------------------------------------------------
__global__ __launch_bounds__(256) void rowcolmax_kernel(
    const float* __restrict__ a2, float* __restrict__ scal)
{
  int h = blockIdx.x >> 1, mode = blockIdx.x & 1, t = threadIdx.x;
  int w = t >> 6, lane = t & 63;
  float sum = 0.f;
  if (mode == 0) {
    const float* p = a2 + ((size_t)h * NLM + t) * NLM;
    for (int j = 0; j < NLM; ++j) sum += p[j];
  } else {
    const float* p = a2 + (size_t)h * NLM * NLM + t;
    for (int i = 0; i < NLM; ++i) sum += p[(size_t)i * NLM];
  }
  float mx = warpMax(sum);
  __shared__ float wr[4];
  if (lane == 0) wr[w] = mx;
  __syncthreads();
  if (t == 0) {
    float m2 = fmaxf(fmaxf(wr[0], wr[1]), fmaxf(wr[2], wr[3]));
    atomicMax((int*)&scal[mode], __float_as_int(m2));
  }
}

__global__ __launch_bounds__(256) void initz_kernel(
    const float* __restrict__ a2, const float* __restrict__ scal, float* __restrict__ z)
{
  int i = blockIdx.x, h = blockIdx.y, t = threadIdx.x;
  float inv = 1.f / (scal[0] * scal[1]);
  z[((size_t)h * NLM + i) * NLM + t] = a2[((size_t)h * NLM + t) * NLM + i] * inv;
}

// ---------------------------------------------------------------------------
// a3@v pipeline (replaces flash_a3v):
// ST[z][j][i] = K[h][j] . QLM[h][i]  (scores^T, per 4-head chunk)
__global__ __launch_bounds__(256) void st_gemm_kernel(
    const float* __restrict__ K, const float* __restrict__ QLM,
    float* __restrict__ ST, int hbase)
{
  const int z = blockIdx.z, h = hbase + z;
  const float* A  = K   + (size_t)h * NPD * 64;
  const float* Bq = QLM + (size_t)h * NLM * 64;
  float* C = ST + (size_t)z * NPD * NLM;
  __shared__ float As[16][132];
  __shared__ float Bs[16][132];
  const int tid = threadIdx.x;
  const int tx = tid & 15, ty = tid >> 4;
  const int bm = blockIdx.y * 128, bn = blockIdx.x * 128;   // bm: j, bn: i
  float acc[8][8] = {};
  for (int k0 = 0; k0 < 64; k0 += 16) {
    float ra[8], rb[8];
    #pragma unroll
    for (int i = 0; i < 8; ++i) {
      int e = tid + 256 * i;
      ra[i] = A[(size_t)(bm + (e >> 4)) * 64 + k0 + (e & 15)];
      rb[i] = Bq[(size_t)(bn + (e & 127)) * 64 + k0 + (e >> 7)];  // QLM^T (L2-hot)
    }
    __syncthreads();
    #pragma unroll
    for (int i = 0; i < 8; ++i) {
      int e = tid + 256 * i;
      As[e & 15][e >> 4]  = ra[i];
      Bs[e >> 7][e & 127] = rb[i];
    }
    __syncthreads();
    #pragma unroll
    for (int k = 0; k < 16; ++k) {
      float4 a0 = *(const float4*)&As[k][ty*4];
      float4 a1 = *(const float4*)&As[k][64 + ty*4];
      float4 b0 = *(const float4*)&Bs[k][tx*4];
      float4 b1 = *(const float4*)&Bs[k][64 + tx*4];
      float av[8] = {a0.x,a0.y,a0.z,a0.w,a1.x,a1.y,a1.z,a1.w};
      float bv[8] = {b0.x,b0.y,b0.z,b0.w,b1.x,b1.y,b1.z,b1.w};
      #pragma unroll
      for (int i = 0; i < 8; ++i)
        #pragma unroll
        for (int j = 0; j < 8; ++j)
          acc[i][j] += av[i] * bv[j];
    }
  }
  #pragma unroll
  for (int i = 0; i < 8; ++i) {
    int r = bm + ((i < 4) ? (ty*4 + i) : (64 + ty*4 + (i - 4)));
    #pragma unroll
    for (int jh = 0; jh < 2; ++jh) {
      int c0 = bn + jh*64 + tx*4;
      float4 v = {acc[i][jh*4+0], acc[i][jh*4+1], acc[i][jh*4+2], acc[i][jh*4+3]};
      *(float4*)&C[(size_t)r * NLM + c0] = v;
    }
  }
}

// per-(chunk, z): PMAX[z][c][i] = max over 256 j of ST[z][c*256+j][i]
__global__ __launch_bounds__(256) void smax1_kernel(
    const float* __restrict__ ST, float* __restrict__ PMAX)
{
  int c = blockIdx.x, z = blockIdx.y, i = threadIdx.x;
  const float* p = ST + (size_t)z * NPD * NLM + (size_t)c * 256 * NLM + i;
  float mx = -INFINITY;
  #pragma unroll 8
  for (int jj = 0; jj < 256; ++jj) mx = fmaxf(mx, p[(size_t)jj * NLM]);
  PMAX[((size_t)z * NCHK + c) * NLM + i] = mx;
}

__global__ __launch_bounds__(256) void smax2_kernel(
    const float* __restrict__ PMAX, float* __restrict__ MXB, int hbase)
{
  int z = blockIdx.x, i = threadIdx.x;
  float mx = -INFINITY;
  for (int c = 0; c < NCHK; ++c)
    mx = fmaxf(mx, PMAX[((size_t)z * NCHK + c) * NLM + i]);
  MXB[(size_t)(hbase + z) * NLM + i] = mx;
}

// split-K PV: AVACC[h][i][d] += sum_j exp(ST[z][j][i]-MX[h][i]) * V[h][j][d],
// LSACC[h][i] += sum_j p. Block: (j-chunk, i-tile of 64, z).
__global__ __launch_bounds__(256) void pv_kernel(
    const float* __restrict__ ST, const float* __restrict__ V,
    const float* __restrict__ MXB, float* __restrict__ AVACC,
    float* __restrict__ LSACC, int hbase)
{
  const int z = blockIdx.z, h = hbase + z;
  const int i0 = blockIdx.y * 64;
  const int j0 = blockIdx.x * JLEN;
  const float* STh = ST + (size_t)z * NPD * NLM;
  const float* Vh  = V  + (size_t)h * NPD * 64;
  const int tid = threadIdx.x, tx = tid & 15, ty = tid >> 4;
  const int il = tid & 63;                 // i-lane this thread stages
  const float mloc = MXB[(size_t)h * NLM + i0 + il];
  __shared__ float As[16][68];             // [j][i]  (p values)
  __shared__ float Bs[16][64];             // [j][d]
  __shared__ float S4[4][64];
  float acc[4][4] = {};
  float psum = 0.f;
  for (int k0 = 0; k0 < JLEN; k0 += 16) {
    float pa[4], pb[4];
    #pragma unroll
    for (int r = 0; r < 4; ++r) {
      int jj = (tid >> 6) + 4 * r;         // 0..15
      int j  = j0 + k0 + jj;
      pa[r] = expf(STh[(size_t)j * NLM + i0 + il] - mloc);
      pb[r] = Vh[(size_t)j * 64 + il];
      psum += pa[r];
    }
    __syncthreads();
    #pragma unroll
    for (int r = 0; r < 4; ++r) {
      int jj = (tid >> 6) + 4 * r;
      As[jj][il] = pa[r];
      Bs[jj][il] = pb[r];
    }
    __syncthreads();
    #pragma unroll
    for (int k = 0; k < 16; ++k) {
      float4 a = *(const float4*)&As[k][ty*4];
      float4 b = *(const float4*)&Bs[k][tx*4];
      float av[4] = {a.x,a.y,a.z,a.w};
      float bv[4] = {b.x,b.y,b.z,b.w};
      #pragma unroll
      for (int i = 0; i < 4; ++i)
        #pragma unroll
        for (int j = 0; j < 4; ++j)
          acc[i][j] += av[i] * bv[j];
    }
    __syncthreads();
  }
  S4[tid >> 6][il] = psum;
  __syncthreads();
  if (tid < 64)
    atomicAdd(&LSACC[(size_t)h * NLM + i0 + tid],
              S4[0][tid] + S4[1][tid] + S4[2][tid] + S4[3][tid]);
  #pragma unroll
  for (int i = 0; i < 4; ++i)
    #pragma unroll
    for (int d = 0; d < 4; ++d)
      atomicAdd(&AVACC[((size_t)h * NLM + i0 + ty*4 + i) * 64 + tx*4 + d], acc[i][d]);
}

__global__ __launch_bounds__(64) void avnorm_kernel(
    const float* __restrict__ AVACC, const float* __restrict__ LSACC,
    float* __restrict__ AV)
{
  int m = blockIdx.x, h = blockIdx.y, d = threadIdx.x;
  size_t idx = ((size_t)h * NLM + m) * 64 + d;
  AV[idx] = AVACC[idx] / LSACC[(size_t)h * NLM + m];
}

// ---------------------------------------------------------------------------
__global__ __launch_bounds__(256) void a1_fused_kernel(
    const float* __restrict__ Q, const float* __restrict__ klm,
    const float* __restrict__ W, float* __restrict__ O1)
{
  int h = blockIdx.y;
  int rb = blockIdx.x * 8;
  int t = threadIdx.x;
  int w = t >> 6, lane = t & 63;
  __shared__ float qs[8][64];
  __shared__ float ps[8][256];
  __shared__ float Wl[128 * 64];
  for (int e = t; e < 8 * 64; e += 256) {
    int r = e >> 6, d2 = e & 63;
    qs[r][d2] = Q[((size_t)h * NPD + PADF + rb + r) * 64 + d2];
  }
  __syncthreads();
  const float* kr = klm + ((size_t)h * NLM + t) * 64;
  float s[8] = {};
  #pragma unroll
  for (int d2 = 0; d2 < 64; d2 += 4) {
    float4 kv = *(const float4*)(kr + d2);
    #pragma unroll
    for (int r = 0; r < 8; ++r)
      s[r] += qs[r][d2]*kv.x + qs[r][d2+1]*kv.y + qs[r][d2+2]*kv.z + qs[r][d2+3]*kv.w;
  }
  #pragma unroll
  for (int r = 0; r < 8; ++r) ps[r][t] = s[r];
  __syncthreads();
  for (int r = w; r < 8; r += 4) {
    float v0 = ps[r][lane], v1 = ps[r][lane+64], v2 = ps[r][lane+128], v3 = ps[r][lane+192];
    float mx = warpMax(fmaxf(fmaxf(v0, v1), fmaxf(v2, v3)));
    float e0 = expf(v0-mx), e1 = expf(v1-mx), e2 = expf(v2-mx), e3 = expf(v3-mx);
    float inv = 1.f / warpSum(e0 + e1 + e2 + e3);
    ps[r][lane] = e0*inv; ps[r][lane+64] = e1*inv; ps[r][lane+128] = e2*inv; ps[r][lane+192] = e3*inv;
  }
  const float* Wh = W + (size_t)h * NLM * 64;
  int r0 = t >> 6, d = t & 63;
  float accA = 0.f, accB = 0.f;
  for (int half = 0; half < 2; ++half) {
    __syncthreads();
    for (int e = t; e < 2048; e += 256)
      ((float4*)Wl)[e] = ((const float4*)(Wh + (size_t)half * 8192))[e];
    __syncthreads();
    #pragma unroll 16
    for (int j = 0; j < 128; ++j) {
      float wv = Wl[j * 64 + d];
      accA += ps[r0][half*128 + j] * wv;
      accB += ps[r0 + 4][half*128 + j] * wv;
    }
  }
  O1[((size_t)rb + r0) * 512 + h*64 + d] = accA;
  O1[((size_t)rb + r0 + 4) * 512 + h*64 + d] = accB;
}

// ---------------------------------------------------------------------------
__global__ __launch_bounds__(512) void conv_res_kernel(
    const float* __restrict__ V, const float* __restrict__ rw, float* __restrict__ O1)
{
  int t = threadIdx.x;
  int h = t >> 6, d = t & 63;
  int i = PADF + blockIdx.x;
  __shared__ float wsm[264];
  if (t < 264) wsm[t] = rw[t];
  __syncthreads();
  const float* vp = V + ((size_t)h * NPD + i - 16) * 64 + d;
  float acc = 0.f;
  #pragma unroll
  for (int k = 0; k < 33; ++k) {
    int row = i - 16 + k;
    float vv = (row < NPD) ? vp[(size_t)k * 64] : 0.f;
    acc += wsm[h*33 + k] * vv;
  }
  O1[(size_t)blockIdx.x * 512 + t] += acc;
}

// ---------------------------------------------------------------------------
__global__ __launch_bounds__(256) void edge_kernel(
    const float* __restrict__ Q2, const float* __restrict__ K2,
    const int* __restrict__ rows, const int* __restrict__ cols,
    const float* __restrict__ vals, float* __restrict__ A_raw)
{
  int e = blockIdx.x * 4 + (threadIdx.x >> 6);
  int lane = threadIdx.x & 63;
  int r = rows[e], c = cols[e];
  float4 q = *(const float4*)&Q2[(size_t)r * 256 + lane * 4];
  float4 k = *(const float4*)&K2[(size_t)c * 256 + lane * 4];
  float s = q.x*k.x + q.y*k.y + q.z*k.z + q.w*k.w;
  s = warpSum(s);
  if (lane == 0) atomicAdd(&A_raw[r], s * 0.0625f * vals[e]);
}

__global__ __launch_bounds__(1024) void softmax_vec_kernel(
    const float* __restrict__ x, float* __restrict__ y)
{
  __shared__ float red[1024];
  int t = threadIdx.x;
  float mx = -INFINITY;
  for (int i = t; i < NTOK; i += 1024) mx = fmaxf(mx, x[i]);
  red[t] = mx; __syncthreads();
  for (int s = 512; s > 0; s >>= 1) { if (t < s) red[t] = fmaxf(red[t], red[t+s]); __syncthreads(); }
  mx = red[0]; __syncthreads();
  float sm = 0.f;
  for (int i = t; i < NTOK; i += 1024) sm += expf(x[i] - mx);
  red[t] = sm; __syncthreads();
  for (int s = 512; s > 0; s >>= 1) { if (t < s) red[t] += red[t+s]; __syncthreads(); }
  sm = red[0];
  float inv = 1.f / sm;
  for (int i = t; i < NTOK; i += 1024) y[i] = expf(x[i] - mx) * inv;
}

__global__ __launch_bounds__(256) void xo_kernel(
    const float* __restrict__ alpha, float* __restrict__ VAL, const float* __restrict__ EO)
{
  int row = blockIdx.x, t = threadIdx.x;
  float a = alpha[row];
  size_t base = (size_t)row * 1024 + t * 4;
  float4 v = *(const float4*)&VAL[base];
  float4 e = *(const float4*)&EO[base];
  float xv[4] = {v.x, v.y, v.z, v.w};
  float ev[4] = {e.x, e.y, e.z, e.w};
  float xo[4];
  #pragma unroll
  for (int i = 0; i < 4; ++i) {
    float xl = a * xv[i];
    float sg = 1.f / (1.f + expf(xl));
    float sw = sg * sg;
    xo[i] = xl * 2.f * sw + 2.f * ev[i] * (1.f - sw);
  }
  float4 r = {xo[0], xo[1], xo[2], xo[3]};
  *(float4*)&VAL[base] = r;
}

__global__ void ones_kernel(float* __restrict__ p, int n)
{
  int i = blockIdx.x * 256 + threadIdx.x;
  if (i < n) p[i] = 1.f;
}

__global__ __launch_bounds__(256) void pooled_kernel(
    const float* __restrict__ XO, float* __restrict__ pool)
{
  int c = blockIdx.x * 256 + threadIdx.x;
  int r0 = blockIdx.y * 500;
  float acc = 0.f;
  for (int r = r0; r < r0 + 500; ++r) acc += XO[(size_t)r * DIM + c];
  atomicAdd(&pool[c], acc);
}

__global__ __launch_bounds__(128) void final_kernel(
    const float* __restrict__ pool, const float* __restrict__ fcw,
    const float* __restrict__ fcb, const float* __restrict__ fcb2,
    float* __restrict__ out)
{
  int t = threadIdx.x, c = t >> 6, lane = t & 63;
  float acc = 0.f;
  for (int d = lane; d < DIM; d += 64)
    acc += pool[d] * (1.f / (float)NTOK) * fcw[d * 2 + c];
  acc = warpSum(acc);
  if (lane == 0) out[c] = acc + fcb[c] + fcb2[c];
}

// ---------------------------------------------------------------------------
extern "C" void kernel_launch(void* const* d_in, const int* in_sizes, int n_in,
                              void* d_out, int out_size, void* d_ws, size_t ws_size,
                              hipStream_t stream)
{
  float* out = (float*)d_out;

  // ---- workspace arena with aliasing (peak ~263 MB) ----
  constexpr size_t QKV_SZ = (size_t)NH * NPD * DH;   // 10,354,688 floats
  constexpr size_t O1_SZ  = (size_t)NTOK * 512;      // 10,240,000
  constexpr size_t EO_SZ  = (size_t)NTOK * DIM;      // 20,480,000
  float* w = (float*)d_ws;
  size_t o = 0;
  auto alloc = [&](size_t n) { float* p = w + o; o += (n + 3) & ~(size_t)3; return p; };
  float* Q    = alloc(QKV_SZ);
  float* K    = alloc(QKV_SZ);
  float* V    = alloc(QKV_SZ);     // VAL later aliases [V, V+EO_SZ) (V+O1+EO window)
  float* O1   = alloc(O1_SZ);      // ST (4-head S^T chunk, 20.71M) aliases O1+EO
  float* EO   = alloc(EO_SZ);
  float* QLM  = alloc((size_t)NH * NLM * DH);
  float* KLM  = alloc((size_t)NH * NLM * DH);
  float* A2   = alloc((size_t)NH * NLM * NLM);
  float* Z0   = alloc((size_t)NH * NLM * NLM);
  float* Z1   = alloc((size_t)NH * NLM * NLM);
  float* T1   = alloc((size_t)NH * NLM * NLM);
  float* T2   = alloc((size_t)NH * NLM * NLM);
  float* T3   = alloc((size_t)NH * NLM * NLM);
  float* AV   = alloc((size_t)NH * NLM * DH);
  float* WM   = alloc((size_t)NH * NLM * DH);
  float* ALPHA= alloc(NTOK);
  float* POOL = alloc(1024);
  float* SCAL = alloc(8);
  float* PMAX = alloc((size_t)4 * NCHK * NLM);   // 80,896
  float* MXB  = alloc((size_t)NH * NLM);         // 2,048
  float* AVACC= alloc((size_t)NH * NLM * DH);    // 131,072
  float* LSACC= alloc((size_t)NH * NLM);         // 2,048
  const size_t needed_bytes = o * sizeof(float);

  // Aliases (lifetimes: ST chunk lives only between st_gemm and pv, before
  // a1_fused writes O1 / EO gemm writes EO. V dead after conv_res; O1 dead
  // after EO gemm; Q dead after a1_fused; K dead after pv+st_gemm.)
  float* ST  = O1;     // needs 4*NPD*NLM = 20,709,376 <= O1_SZ+EO_SZ ✓
  float* VAL = V;      // V+O1 window >= EO_SZ ✓
  float* Q2  = Q;      // [NTOK,256]
  float* K2  = K;

  // Fail cleanly (zeros) instead of faulting if environment differs from spec.
  if (n_in < 23 || ws_size < needed_bytes || out_size < 2 + NTOK + NTOK) {
    int grid = out_size > 0 ? (out_size + 255) / 256 : 1;
    zero_kernel<<<grid, 256, 0, stream>>>(out, out_size);
    return;
  }

  const float* bag  = (const float*)d_in[0];
  const float* adjv = (const float*)d_in[1];
  const float* qkvw = (const float*)d_in[2];
  const float* outw = (const float*)d_in[3];
  const float* outb = (const float*)d_in[4];
  const float* resw = (const float*)d_in[5];
  const float* wqw  = (const float*)d_in[6];
  const float* wqb  = (const float*)d_in[7];
  const float* wkw  = (const float*)d_in[8];
  const float* wkb  = (const float*)d_in[9];
  const float* wvw  = (const float*)d_in[10];
  const float* wvb  = (const float*)d_in[11];
  // d_in[12..17]: va/ua/wa — dead (k_alpha = softmax over singleton axis = 1.0)
  const float* fcw  = (const float*)d_in[18];
  const float* fcb  = (const float*)d_in[19];
  const float* fcb2 = (const float*)d_in[20];
  const int* arows  = (const int*)d_in[21];
  const int* acols  = (const int*)d_in[22];

  float* A_raw  = out + 2;
  float* kalpha = A_raw + NTOK;

  zero_kernel<<<(NTOK + 255) / 256, 256, 0, stream>>>(A_raw, NTOK);
  zero_kernel<<<4, 256, 0, stream>>>(POOL, 1024);
  zero_kernel<<<1, 256, 0, stream>>>(SCAL, 8);
  zero_kernel<<<(131072 + 255) / 256, 256, 0, stream>>>(AVACC, 131072);
  zero_kernel<<<8, 256, 0, stream>>>(LSACC, 2048);

  // --- Nystrom encoder ---
  gemm_qkv_kernel<<<dim3(1536/128, NPD/128), 256, 0, stream>>>(bag, qkvw, Q, K, V);
  landmark_kernel<<<dim3(NLM, NH), 64, 0, stream>>>(Q, QLM);
  landmark_kernel<<<dim3(NLM, NH), 64, 0, stream>>>(K, KLM);
  a2_kernel<<<dim3(NLM, NH), 256, 0, stream>>>(QLM, KLM, A2);
  rowcolmax_kernel<<<16, 256, 0, stream>>>(A2, SCAL);
  initz_kernel<<<dim3(NLM, NH), 256, 0, stream>>>(A2, SCAL, Z0);

  auto bgemm = [&](const float* Ab, const float* Bb, float* Cb,
                   int Ms, int Ns, int Ks, float dval, int useDiag, float scale) {
    bgemm64_kernel<<<dim3(Ns/64, Ms/64, NH), 256, 0, stream>>>(Ab, Bb, Cb, Ms, Ns, Ks, dval, useDiag, scale);
  };
  float* zc = Z0; float* zn = Z1;
  for (int it = 0; it < PITERS; ++it) {
    bgemm(A2, zc, T1, NLM, NLM, NLM, 0.f,  0, 1.f);    // T1 = X @ Z
    bgemm(T1, T1, T2, NLM, NLM, NLM, 7.f,  1, 1.f);    // T2 = T1 @ (7I - T1)
    bgemm(T1, T2, T3, NLM, NLM, NLM, 15.f, 1, 1.f);    // T3 = T1 @ (15I - T2)
    bgemm(zc, T3, zn, NLM, NLM, NLM, 13.f, 1, 0.25f);  // Z' = 0.25 Z @ (13I - T3)
    float* tmp = zc; zc = zn; zn = tmp;
  }

  // --- a3@v via materialized S^T (2 chunks of 4 heads) ---
  for (int hb = 0; hb < NH; hb += 4) {
    st_gemm_kernel<<<dim3(NLM/128, NPD/128, 4), 256, 0, stream>>>(K, QLM, ST, hb);
    smax1_kernel<<<dim3(NCHK, 4), 256, 0, stream>>>(ST, PMAX);
    smax2_kernel<<<4, 256, 0, stream>>>(PMAX, MXB, hb);
    pv_kernel<<<dim3(JSPL, NLM/64, 4), 256, 0, stream>>>(ST, V, MXB, AVACC, LSACC, hb);
  }
  avnorm_kernel<<<dim3(NLM, NH), 64, 0, stream>>>(AVACC, LSACC, AV);

  bgemm(zc, AV, WM, NLM, DH, NLM, 0.f, 0, 1.f);        // W = pinv(a2) @ (a3@v)
  a1_fused_kernel<<<dim3(NTOK/8, NH), 256, 0, stream>>>(Q, KLM, WM, O1);
  conv_res_kernel<<<NTOK, 512, 0, stream>>>(V, resw, O1);
  gemm_f32_kernel<<<dim3(DIM/128, (NTOK+127)/128), 256, 0, stream>>>(
      O1, outw, outb, bag, EO, NTOK, DIM, 512);        // eo = proj(O1)+bag
  // V and O1 are now dead -> their window is VAL from here on.

  // --- CustomAttention + NeighborAggregator ---
  gemm_f32_kernel<<<dim3(256/128, (NTOK+127)/128), 256, 0, stream>>>(
      EO, wqw, wqb, nullptr, Q2, NTOK, 256, DIM);
  gemm_f32_kernel<<<dim3(256/128, (NTOK+127)/128), 256, 0, stream>>>(
      EO, wkw, wkb, nullptr, K2, NTOK, 256, DIM);
  edge_kernel<<<NEDGE/4, 256, 0, stream>>>(Q2, K2, arows, acols, adjv, A_raw);
  softmax_vec_kernel<<<1, 1024, 0, stream>>>(A_raw, ALPHA);

  // --- value / gating / pooling ---
  gemm_f32_kernel<<<dim3(DIM/128, (NTOK+127)/128), 256, 0, stream>>>(
      bag, wvw, wvb, nullptr, VAL, NTOK, DIM, DIM);
  xo_kernel<<<NTOK, 256, 0, stream>>>(ALPHA, VAL, EO);
  ones_kernel<<<(NTOK+255)/256, 256, 0, stream>>>(kalpha, NTOK);
  pooled_kernel<<<dim3(4, 40), 256, 0, stream>>>(VAL, POOL);
  final_kernel<<<1, 128, 0, stream>>>(POOL, fcw, fcb, fcb2, out);
}

// Round 5
// 2563.996 us; speedup vs baseline: 2.4932x; 1.4618x over previous
//
#include <hip/hip_runtime.h>
#include <math.h>

// ---------------------------------------------------------------------------
// CAMIL forward on MI355X. Round 5: big GEMMs moved to fp16x2 split-precision
// MFMA (hi/lo fp16, 3 products -> ~fp32 accuracy at ~3x bf16-MFMA cost).
constexpr int NTOK = 20000;   // N
constexpr int DIM  = 1024;    // D
constexpr int NEDGE= 320000;  // E
constexpr int NH   = 8;       // heads
constexpr int DH   = 64;      // head dim
constexpr int NLM  = 256;     // landmarks M
constexpr int PADF = 224;     // front pad  (M - N%M)
constexpr int NPD  = 20224;   // N + pad
constexpr int LGRP = 79;      // NPD / NLM
constexpr int PITERS = 6;
constexpr int JSPL = 16;              // pv split-K chunks
constexpr int JLEN = NPD / JSPL;      // 1264
constexpr int NCHK = 79;              // smax1 chunks (NPD / 256)

typedef unsigned short u16;
typedef _Float16 f16x8 __attribute__((ext_vector_type(8)));
typedef float    f32x4 __attribute__((ext_vector_type(4)));
typedef u16      u16x8 __attribute__((ext_vector_type(8)));
typedef u16      u16x4 __attribute__((ext_vector_type(4)));

__device__ __forceinline__ float warpSum(float v){
  #pragma unroll
  for (int o = 32; o; o >>= 1) v += __shfl_xor(v, o);
  return v;
}
__device__ __forceinline__ float warpMax(float v){
  #pragma unroll
  for (int o = 32; o; o >>= 1) v = fmaxf(v, __shfl_xor(v, o));
  return v;
}
__device__ __forceinline__ u16 f2h(float x){
  _Float16 h = (_Float16)x; return __builtin_bit_cast(u16, h);
}
__device__ __forceinline__ float h2f(u16 u){
  return (float)__builtin_bit_cast(_Float16, u);
}
__device__ __forceinline__ int swz3(int r){ return (r ^ (r >> 2)) & 3; }

__global__ void zero_kernel(float* __restrict__ p, int n)
{
  int i = blockIdx.x * 256 + threadIdx.x;
  if (i < n) p[i] = 0.f;
}

// ---------------------------------------------------------------------------
// Transpose + fp16 hi/lo split: W[K,N] f32 -> Th,Tl[N,K] fp16-bits.
__global__ __launch_bounds__(256) void tsplit_kernel(
    const float* __restrict__ W, u16* __restrict__ Th, u16* __restrict__ Tl,
    int Kd, int Nd)
{
  __shared__ float tile[32][33];
  const int t = threadIdx.x, bx = blockIdx.x, by = blockIdx.y;
  {
    int kk = t >> 3, n4 = (t & 7) * 4;
    float4 v = *(const float4*)&W[(size_t)(by*32 + kk) * Nd + bx*32 + n4];
    tile[kk][n4+0] = v.x; tile[kk][n4+1] = v.y;
    tile[kk][n4+2] = v.z; tile[kk][n4+3] = v.w;
  }
  __syncthreads();
  int nn = t >> 3, k4 = (t & 7) * 4;
  u16x4 hv, lv;
  #pragma unroll
  for (int c = 0; c < 4; ++c) {
    float x = tile[k4 + c][nn];
    u16 h = f2h(x);
    hv[c] = h;
    lv[c] = f2h(x - h2f(h));
  }
  size_t o = (size_t)(bx*32 + nn) * Kd + by*32 + k4;
  *(u16x4*)&Th[o] = hv;
  *(u16x4*)&Tl[o] = lv;
}

// ---------------------------------------------------------------------------
// fp16x2 split-precision MFMA GEMM.
// C[M,N] = A[M,K] @ B[K,N] (+bias) (+add), A fp32 (split on the fly, rows
// shifted by ashift with zero fill outside [0,arows)), B pre-transposed/split
// as BTh/BTl [N,K]. If Qd!=null: qkv scatter epilogue into Q/K/V [h][NPD][64]
// with Q*0.125. Tile 128x128, BK=32, 4 waves x 4x4 16x16x32 fragments.
__global__ __launch_bounds__(256) void gemm_h2_kernel(
    const float* __restrict__ A, int ashift, int arows,
    const u16* __restrict__ BTh, const u16* __restrict__ BTl,
    const float* __restrict__ bias, const float* __restrict__ add,
    float* __restrict__ C,
    float* __restrict__ Qd, float* __restrict__ Kd2, float* __restrict__ Vd,
    int M, int N, int Kdim)
{
  __shared__ __align__(16) u16 AsH[128*32];
  __shared__ __align__(16) u16 AsL[128*32];
  __shared__ __align__(16) u16 BsH[128*32];
  __shared__ __align__(16) u16 BsL[128*32];
  const int tid = threadIdx.x, lane = tid & 63, wv = tid >> 6;
  const int wr = wv >> 1, wc = wv & 1;
  const int bm = blockIdx.y * 128, bn = blockIdx.x * 128;

  // staging role: row/col = tid>>1 (0..127), k-half = tid&1 (16 elems each)
  const int rowA = tid >> 1, half = tid & 1;
  const int rg = bm + rowA;
  const unsigned r_a = (unsigned)(rg - ashift);
  const bool av = r_a < (unsigned)arows;
  const float* Ap = A + (size_t)r_a * Kdim + half * 16;
  const u16* Bph = BTh + (size_t)(bn + rowA) * Kdim + half * 16;
  const u16* Bpl = BTl + (size_t)(bn + rowA) * Kdim + half * 16;
  const int swa = swz3(rowA);
  const int pg0 = (half*2) ^ swa, pg1 = (half*2 + 1) ^ swa;
  u16* wA_h0 = &AsH[rowA*32 + pg0*8]; u16* wA_h1 = &AsH[rowA*32 + pg1*8];
  u16* wA_l0 = &AsL[rowA*32 + pg0*8]; u16* wA_l1 = &AsL[rowA*32 + pg1*8];
  u16* wB_h0 = &BsH[rowA*32 + pg0*8]; u16* wB_h1 = &BsH[rowA*32 + pg1*8];
  u16* wB_l0 = &BsL[rowA*32 + pg0*8]; u16* wB_l1 = &BsL[rowA*32 + pg1*8];

  f32x4 acc[4][4];
  #pragma unroll
  for (int i = 0; i < 4; ++i)
    #pragma unroll
    for (int j = 0; j < 4; ++j) acc[i][j] = 0;

  const int lg = lane >> 4;      // k-granule of this lane's fragments
  const int l15 = lane & 15;

  for (int kt = 0; kt < Kdim; kt += 32) {
    // ---- load + split A (fp32 -> hi/lo fp16), load pre-split B ----
    float x[16];
    if (av) {
      float4 v0 = *(const float4*)(Ap + kt);
      float4 v1 = *(const float4*)(Ap + kt + 4);
      float4 v2 = *(const float4*)(Ap + kt + 8);
      float4 v3 = *(const float4*)(Ap + kt + 12);
      x[0]=v0.x; x[1]=v0.y; x[2]=v0.z; x[3]=v0.w;
      x[4]=v1.x; x[5]=v1.y; x[6]=v1.z; x[7]=v1.w;
      x[8]=v2.x; x[9]=v2.y; x[10]=v2.z; x[11]=v2.w;
      x[12]=v3.x; x[13]=v3.y; x[14]=v3.z; x[15]=v3.w;
    } else {
      #pragma unroll
      for (int e = 0; e < 16; ++e) x[e] = 0.f;
    }
    u16x8 ah0, ah1, al0, al1;
    #pragma unroll
    for (int e = 0; e < 8; ++e) {
      u16 h = f2h(x[e]);      ah0[e] = h; al0[e] = f2h(x[e]     - h2f(h));
      u16 h2 = f2h(x[8+e]);   ah1[e] = h2; al1[e] = f2h(x[8+e] - h2f(h2));
    }
    u16x8 bh0 = *(const u16x8*)(Bph + kt);
    u16x8 bh1 = *(const u16x8*)(Bph + kt + 8);
    u16x8 bl0 = *(const u16x8*)(Bpl + kt);
    u16x8 bl1 = *(const u16x8*)(Bpl + kt + 8);

    __syncthreads();               // prior tile fully consumed
    *(u16x8*)wA_h0 = ah0; *(u16x8*)wA_h1 = ah1;
    *(u16x8*)wA_l0 = al0; *(u16x8*)wA_l1 = al1;
    *(u16x8*)wB_h0 = bh0; *(u16x8*)wB_h1 = bh1;
    *(u16x8*)wB_l0 = bl0; *(u16x8*)wB_l1 = bl1;
    __syncthreads();

    // ---- fragments + MFMA ----
    f16x8 bh[4], bl[4];
    #pragma unroll
    for (int j = 0; j < 4; ++j) {
      int lb = wc*64 + j*16 + l15;
      int offb = lb*32 + ((lg ^ swz3(lb)) * 8);
      bh[j] = __builtin_bit_cast(f16x8, *(const u16x8*)&BsH[offb]);
      bl[j] = __builtin_bit_cast(f16x8, *(const u16x8*)&BsL[offb]);
    }
    #pragma unroll
    for (int i = 0; i < 4; ++i) {
      int la = wr*64 + i*16 + l15;
      int offa = la*32 + ((lg ^ swz3(la)) * 8);
      f16x8 ah = __builtin_bit_cast(f16x8, *(const u16x8*)&AsH[offa]);
      f16x8 al = __builtin_bit_cast(f16x8, *(const u16x8*)&AsL[offa]);
      #pragma unroll
      for (int j = 0; j < 4; ++j) {
        acc[i][j] = __builtin_amdgcn_mfma_f32_16x16x32_f16(ah, bh[j], acc[i][j], 0, 0, 0);
        acc[i][j] = __builtin_amdgcn_mfma_f32_16x16x32_f16(ah, bl[j], acc[i][j], 0, 0, 0);
        acc[i][j] = __builtin_amdgcn_mfma_f32_16x16x32_f16(al, bh[j], acc[i][j], 0, 0, 0);
      }
    }
  }

  // ---- epilogue ----
  if (Qd) {
    #pragma unroll
    for (int i = 0; i < 4; ++i) {
      int row0 = bm + wr*64 + i*16 + (lane>>4)*4;
      #pragma unroll
      for (int j = 0; j < 4; ++j) {
        int col = bn + wc*64 + j*16 + l15;
        int which = col >> 9;
        float* dst = (which == 0) ? Qd : (which == 1) ? Kd2 : Vd;
        float sc = (which == 0) ? 0.125f : 1.f;
        int h = (col >> 6) & 7, dh = col & 63;
        #pragma unroll
        for (int r = 0; r < 4; ++r) {
          int gr = row0 + r;
          dst[((size_t)h * NPD + gr) * 64 + dh] = acc[i][j][r] * sc;
        }
      }
    }
  } else {
    #pragma unroll
    for (int i = 0; i < 4; ++i) {
      int row0 = bm + wr*64 + i*16 + (lane>>4)*4;
      #pragma unroll
      for (int j = 0; j < 4; ++j) {
        int col = bn + wc*64 + j*16 + l15;
        float bv = bias ? bias[col] : 0.f;
        #pragma unroll
        for (int r = 0; r < 4; ++r) {
          int gr = row0 + r;
          if (gr < M) {
            float v = acc[i][j][r] + bv;
            if (add) v += add[(size_t)gr * N + col];
            C[(size_t)gr * N + col] = v;
          }
        }
      }
    }
  }
}

// ---------------------------------------------------------------------------
// Batched-per-head 64x64-tile GEMM, with optional (dval*I - B) fold + scale.
__global__ __launch_bounds__(256) void bgemm64_kernel(
    const float* __restrict__ A, const float* __restrict__ B, float* __restrict__ C,
    int Msub, int Nsub, int Ksub, float dval, int useDiag, float scale)
{
  const int h = blockIdx.z;
  const float* Ah = A + (size_t)h * Msub * Ksub;
  const float* Bh = B + (size_t)h * Ksub * Nsub;
  float* Ch = C + (size_t)h * Msub * Nsub;
  __shared__ float As[16][68];
  __shared__ float Bs[16][64];
  const int tid = threadIdx.x, tx = tid & 15, ty = tid >> 4;
  const int bm = blockIdx.y * 64, bn = blockIdx.x * 64;
  float acc[4][4] = {};
  for (int k0 = 0; k0 < Ksub; k0 += 16) {
    float ra[4], rb[4];
    #pragma unroll
    for (int i = 0; i < 4; ++i) {
      int e = tid + 256 * i;
      ra[i] = Ah[(size_t)(bm + (e >> 4)) * Ksub + k0 + (e & 15)];
      int brow = k0 + (e >> 6), bcol = bn + (e & 63);
      float bv = Bh[(size_t)brow * Nsub + bcol];
      if (useDiag) bv = ((brow == bcol) ? dval : 0.f) - bv;
      rb[i] = bv;
    }
    __syncthreads();
    #pragma unroll
    for (int i = 0; i < 4; ++i) {
      int e = tid + 256 * i;
      As[e & 15][e >> 4] = ra[i];
      Bs[e >> 6][e & 63] = rb[i];
    }
    __syncthreads();
    #pragma unroll
    for (int k = 0; k < 16; ++k) {
      float4 a = *(const float4*)&As[k][ty*4];
      float4 b = *(const float4*)&Bs[k][tx*4];
      float avv[4] = {a.x,a.y,a.z,a.w};
      float bvv[4] = {b.x,b.y,b.z,b.w};
      #pragma unroll
      for (int i = 0; i < 4; ++i)
        #pragma unroll
        for (int j = 0; j < 4; ++j)
          acc[i][j] += avv[i] * bvv[j];
    }
    __syncthreads();
  }
  #pragma unroll
  for (int i = 0; i < 4; ++i) {
    float4 v = {acc[i][0]*scale, acc[i][1]*scale, acc[i][2]*scale, acc[i][3]*scale};
    *(float4*)&Ch[(size_t)(bm + ty*4 + i) * Nsub + bn + tx*4] = v;
  }
}

// ---------------------------------------------------------------------------
__global__ __launch_bounds__(64) void landmark_kernel(
    const float* __restrict__ src, float* __restrict__ dst)
{
  int m = blockIdx.x, h = blockIdx.y, d = threadIdx.x;
  const float* p = src + ((size_t)h * NPD + (size_t)m * LGRP) * 64 + d;
  float acc = 0.f;
  for (int j = 0; j < LGRP; ++j) acc += p[(size_t)j * 64];
  dst[((size_t)h * NLM + m) * 64 + d] = acc / (float)LGRP;
}

// ---------------------------------------------------------------------------
__global__ __launch_bounds__(256) void a2_kernel(
    const float* __restrict__ qlm, const float* __restrict__ klm, float* __restrict__ a2)
{
  int i = blockIdx.x, h = blockIdx.y, t = threadIdx.x;
  int w = t >> 6, lane = t & 63;
  __shared__ float qs[64];
  __shared__ float wr[4], wr2[4];
  if (t < 64) qs[t] = qlm[((size_t)h * NLM + i) * 64 + t];
  __syncthreads();
  const float* kr = klm + ((size_t)h * NLM + t) * 64;
  float s = 0.f;
  #pragma unroll
  for (int d2 = 0; d2 < 64; d2 += 4) {
    float4 kv = *(const float4*)(kr + d2);
    s += qs[d2]*kv.x + qs[d2+1]*kv.y + qs[d2+2]*kv.z + qs[d2+3]*kv.w;
  }
  float mx = warpMax(s);
  if (lane == 0) wr[w] = mx;
  __syncthreads();
  mx = fmaxf(fmaxf(wr[0], wr[1]), fmaxf(wr[2], wr[3]));
  float e = expf(s - mx);
  float sm = warpSum(e);
  if (lane == 0) wr2[w] = sm;
  __syncthreads();
  sm = wr2[0] + wr2[1] + wr2[2] + wr2[3];
  a2[((size_t)h * NLM + i) * NLM + t] = e / sm;
}

// ---------------------------------------------------------------------------
__global__ __launch_bounds__(256) void rowcolmax_kernel(
    const float* __restrict__ a2, float* __restrict__ scal)
{
  int h = blockIdx.x >> 1, mode = blockIdx.x & 1, t = threadIdx.x;
  int w = t >> 6, lane = t & 63;
  float sum = 0.f;
  if (mode == 0) {
    const float* p = a2 + ((size_t)h * NLM + t) * NLM;
    for (int j = 0; j < NLM; ++j) sum += p[j];
  } else {
    const float* p = a2 + (size_t)h * NLM * NLM + t;
    for (int i = 0; i < NLM; ++i) sum += p[(size_t)i * NLM];
  }
  float mx = warpMax(sum);
  __shared__ float wr[4];
  if (lane == 0) wr[w] = mx;
  __syncthreads();
  if (t == 0) {
    float m2 = fmaxf(fmaxf(wr[0], wr[1]), fmaxf(wr[2], wr[3]));
    atomicMax((int*)&scal[mode], __float_as_int(m2));
  }
}

__global__ __launch_bounds__(256) void initz_kernel(
    const float* __restrict__ a2, const float* __restrict__ scal, float* __restrict__ z)
{
  int i = blockIdx.x, h = blockIdx.y, t = threadIdx.x;
  float inv = 1.f / (scal[0] * scal[1]);
  z[((size_t)h * NLM + i) * NLM + t] = a2[((size_t)h * NLM + t) * NLM + i] * inv;
}

// ---------------------------------------------------------------------------
// a3@v pipeline: ST[z][j][i] = K[h][j].QLM[h][i] (per 4-head chunk)
__global__ __launch_bounds__(256) void st_gemm_kernel(
    const float* __restrict__ K, const float* __restrict__ QLM,
    float* __restrict__ ST, int hbase)
{
  const int z = blockIdx.z, h = hbase + z;
  const float* A  = K   + (size_t)h * NPD * 64;
  const float* Bq = QLM + (size_t)h * NLM * 64;
  float* C = ST + (size_t)z * NPD * NLM;
  __shared__ float As[16][132];
  __shared__ float Bs[16][132];
  const int tid = threadIdx.x;
  const int tx = tid & 15, ty = tid >> 4;
  const int bm = blockIdx.y * 128, bn = blockIdx.x * 128;
  float acc[8][8] = {};
  for (int k0 = 0; k0 < 64; k0 += 16) {
    float ra[8], rb[8];
    #pragma unroll
    for (int i = 0; i < 8; ++i) {
      int e = tid + 256 * i;
      ra[i] = A[(size_t)(bm + (e >> 4)) * 64 + k0 + (e & 15)];
      rb[i] = Bq[(size_t)(bn + (e & 127)) * 64 + k0 + (e >> 7)];
    }
    __syncthreads();
    #pragma unroll
    for (int i = 0; i < 8; ++i) {
      int e = tid + 256 * i;
      As[e & 15][e >> 4]  = ra[i];
      Bs[e >> 7][e & 127] = rb[i];
    }
    __syncthreads();
    #pragma unroll
    for (int k = 0; k < 16; ++k) {
      float4 a0 = *(const float4*)&As[k][ty*4];
      float4 a1 = *(const float4*)&As[k][64 + ty*4];
      float4 b0 = *(const float4*)&Bs[k][tx*4];
      float4 b1 = *(const float4*)&Bs[k][64 + tx*4];
      float av[8] = {a0.x,a0.y,a0.z,a0.w,a1.x,a1.y,a1.z,a1.w};
      float bv[8] = {b0.x,b0.y,b0.z,b0.w,b1.x,b1.y,b1.z,b1.w};
      #pragma unroll
      for (int i = 0; i < 8; ++i)
        #pragma unroll
        for (int j = 0; j < 8; ++j)
          acc[i][j] += av[i] * bv[j];
    }
  }
  #pragma unroll
  for (int i = 0; i < 8; ++i) {
    int r = bm + ((i < 4) ? (ty*4 + i) : (64 + ty*4 + (i - 4)));
    #pragma unroll
    for (int jh = 0; jh < 2; ++jh) {
      int c0 = bn + jh*64 + tx*4;
      float4 v = {acc[i][jh*4+0], acc[i][jh*4+1], acc[i][jh*4+2], acc[i][jh*4+3]};
      *(float4*)&C[(size_t)r * NLM + c0] = v;
    }
  }
}

__global__ __launch_bounds__(256) void smax1_kernel(
    const float* __restrict__ ST, float* __restrict__ PMAX)
{
  int c = blockIdx.x, z = blockIdx.y, i = threadIdx.x;
  const float* p = ST + (size_t)z * NPD * NLM + (size_t)c * 256 * NLM + i;
  float mx = -INFINITY;
  #pragma unroll 8
  for (int jj = 0; jj < 256; ++jj) mx = fmaxf(mx, p[(size_t)jj * NLM]);
  PMAX[((size_t)z * NCHK + c) * NLM + i] = mx;
}

__global__ __launch_bounds__(256) void smax2_kernel(
    const float* __restrict__ PMAX, float* __restrict__ MXB, int hbase)
{
  int z = blockIdx.x, i = threadIdx.x;
  float mx = -INFINITY;
  for (int c = 0; c < NCHK; ++c)
    mx = fmaxf(mx, PMAX[((size_t)z * NCHK + c) * NLM + i]);
  MXB[(size_t)(hbase + z) * NLM + i] = mx;
}

__global__ __launch_bounds__(256) void pv_kernel(
    const float* __restrict__ ST, const float* __restrict__ V,
    const float* __restrict__ MXB, float* __restrict__ AVACC,
    float* __restrict__ LSACC, int hbase)
{
  const int z = blockIdx.z, h = hbase + z;
  const int i0 = blockIdx.y * 64;
  const int j0 = blockIdx.x * JLEN;
  const float* STh = ST + (size_t)z * NPD * NLM;
  const float* Vh  = V  + (size_t)h * NPD * 64;
  const int tid = threadIdx.x, tx = tid & 15, ty = tid >> 4;
  const int il = tid & 63;
  const float mloc = MXB[(size_t)h * NLM + i0 + il];
  __shared__ float As[16][68];
  __shared__ float Bs[16][64];
  __shared__ float S4[4][64];
  float acc[4][4] = {};
  float psum = 0.f;
  for (int k0 = 0; k0 < JLEN; k0 += 16) {
    float pa[4], pb[4];
    #pragma unroll
    for (int r = 0; r < 4; ++r) {
      int jj = (tid >> 6) + 4 * r;
      int j  = j0 + k0 + jj;
      pa[r] = expf(STh[(size_t)j * NLM + i0 + il] - mloc);
      pb[r] = Vh[(size_t)j * 64 + il];
      psum += pa[r];
    }
    __syncthreads();
    #pragma unroll
    for (int r = 0; r < 4; ++r) {
      int jj = (tid >> 6) + 4 * r;
      As[jj][il] = pa[r];
      Bs[jj][il] = pb[r];
    }
    __syncthreads();
    #pragma unroll
    for (int k = 0; k < 16; ++k) {
      float4 a = *(const float4*)&As[k][ty*4];
      float4 b = *(const float4*)&Bs[k][tx*4];
      float av[4] = {a.x,a.y,a.z,a.w};
      float bv[4] = {b.x,b.y,b.z,b.w};
      #pragma unroll
      for (int i = 0; i < 4; ++i)
        #pragma unroll
        for (int j = 0; j < 4; ++j)
          acc[i][j] += av[i] * bv[j];
    }
    __syncthreads();
  }
  S4[tid >> 6][il] = psum;
  __syncthreads();
  if (tid < 64)
    atomicAdd(&LSACC[(size_t)h * NLM + i0 + tid],
              S4[0][tid] + S4[1][tid] + S4[2][tid] + S4[3][tid]);
  #pragma unroll
  for (int i = 0; i < 4; ++i)
    #pragma unroll
    for (int d = 0; d < 4; ++d)
      atomicAdd(&AVACC[((size_t)h * NLM + i0 + ty*4 + i) * 64 + tx*4 + d], acc[i][d]);
}

__global__ __launch_bounds__(64) void avnorm_kernel(
    const float* __restrict__ AVACC, const float* __restrict__ LSACC,
    float* __restrict__ AV)
{
  int m = blockIdx.x, h = blockIdx.y, d = threadIdx.x;
  size_t idx = ((size_t)h * NLM + m) * 64 + d;
  AV[idx] = AVACC[idx] / LSACC[(size_t)h * NLM + m];
}

// ---------------------------------------------------------------------------
__global__ __launch_bounds__(256) void a1_fused_kernel(
    const float* __restrict__ Q, const float* __restrict__ klm,
    const float* __restrict__ W, float* __restrict__ O1)
{
  int h = blockIdx.y;
  int rb = blockIdx.x * 8;
  int t = threadIdx.x;
  int w = t >> 6, lane = t & 63;
  __shared__ float qs[8][64];
  __shared__ float ps[8][256];
  __shared__ float Wl[128 * 64];
  for (int e = t; e < 8 * 64; e += 256) {
    int r = e >> 6, d2 = e & 63;
    qs[r][d2] = Q[((size_t)h * NPD + PADF + rb + r) * 64 + d2];
  }
  __syncthreads();
  const float* kr = klm + ((size_t)h * NLM + t) * 64;
  float s[8] = {};
  #pragma unroll
  for (int d2 = 0; d2 < 64; d2 += 4) {
    float4 kv = *(const float4*)(kr + d2);
    #pragma unroll
    for (int r = 0; r < 8; ++r)
      s[r] += qs[r][d2]*kv.x + qs[r][d2+1]*kv.y + qs[r][d2+2]*kv.z + qs[r][d2+3]*kv.w;
  }
  #pragma unroll
  for (int r = 0; r < 8; ++r) ps[r][t] = s[r];
  __syncthreads();
  for (int r = w; r < 8; r += 4) {
    float v0 = ps[r][lane], v1 = ps[r][lane+64], v2 = ps[r][lane+128], v3 = ps[r][lane+192];
    float mx = warpMax(fmaxf(fmaxf(v0, v1), fmaxf(v2, v3)));
    float e0 = expf(v0-mx), e1 = expf(v1-mx), e2 = expf(v2-mx), e3 = expf(v3-mx);
    float inv = 1.f / warpSum(e0 + e1 + e2 + e3);
    ps[r][lane] = e0*inv; ps[r][lane+64] = e1*inv; ps[r][lane+128] = e2*inv; ps[r][lane+192] = e3*inv;
  }
  const float* Wh = W + (size_t)h * NLM * 64;
  int r0 = t >> 6, d = t & 63;
  float accA = 0.f, accB = 0.f;
  for (int half = 0; half < 2; ++half) {
    __syncthreads();
    for (int e = t; e < 2048; e += 256)
      ((float4*)Wl)[e] = ((const float4*)(Wh + (size_t)half * 8192))[e];
    __syncthreads();
    #pragma unroll 16
    for (int j = 0; j < 128; ++j) {
      float wv = Wl[j * 64 + d];
      accA += ps[r0][half*128 + j] * wv;
      accB += ps[r0 + 4][half*128 + j] * wv;
    }
  }
  O1[((size_t)rb + r0) * 512 + h*64 + d] = accA;
  O1[((size_t)rb + r0 + 4) * 512 + h*64 + d] = accB;
}

// ---------------------------------------------------------------------------
__global__ __launch_bounds__(512) void conv_res_kernel(
    const float* __restrict__ V, const float* __restrict__ rw, float* __restrict__ O1)
{
  int t = threadIdx.x;
  int h = t >> 6, d = t & 63;
  int i = PADF + blockIdx.x;
  __shared__ float wsm[264];
  if (t < 264) wsm[t] = rw[t];
  __syncthreads();
  const float* vp = V + ((size_t)h * NPD + i - 16) * 64 + d;
  float acc = 0.f;
  #pragma unroll
  for (int k = 0; k < 33; ++k) {
    int row = i - 16 + k;
    float vv = (row < NPD) ? vp[(size_t)k * 64] : 0.f;
    acc += wsm[h*33 + k] * vv;
  }
  O1[(size_t)blockIdx.x * 512 + t] += acc;
}

// ---------------------------------------------------------------------------
__global__ __launch_bounds__(256) void edge_kernel(
    const float* __restrict__ Q2, const float* __restrict__ K2,
    const int* __restrict__ rows, const int* __restrict__ cols,
    const float* __restrict__ vals, float* __restrict__ A_raw)
{
  int e = blockIdx.x * 4 + (threadIdx.x >> 6);
  int lane = threadIdx.x & 63;
  int r = rows[e], c = cols[e];
  float4 q = *(const float4*)&Q2[(size_t)r * 256 + lane * 4];
  float4 k = *(const float4*)&K2[(size_t)c * 256 + lane * 4];
  float s = q.x*k.x + q.y*k.y + q.z*k.z + q.w*k.w;
  s = warpSum(s);
  if (lane == 0) atomicAdd(&A_raw[r], s * 0.0625f * vals[e]);
}

__global__ __launch_bounds__(1024) void softmax_vec_kernel(
    const float* __restrict__ x, float* __restrict__ y)
{
  __shared__ float red[1024];
  int t = threadIdx.x;
  float mx = -INFINITY;
  for (int i = t; i < NTOK; i += 1024) mx = fmaxf(mx, x[i]);
  red[t] = mx; __syncthreads();
  for (int s = 512; s > 0; s >>= 1) { if (t < s) red[t] = fmaxf(red[t], red[t+s]); __syncthreads(); }
  mx = red[0]; __syncthreads();
  float sm = 0.f;
  for (int i = t; i < NTOK; i += 1024) sm += expf(x[i] - mx);
  red[t] = sm; __syncthreads();
  for (int s = 512; s > 0; s >>= 1) { if (t < s) red[t] += red[t+s]; __syncthreads(); }
  sm = red[0];
  float inv = 1.f / sm;
  for (int i = t; i < NTOK; i += 1024) y[i] = expf(x[i] - mx) * inv;
}

__global__ __launch_bounds__(256) void xo_kernel(
    const float* __restrict__ alpha, float* __restrict__ VAL, const float* __restrict__ EO)
{
  int row = blockIdx.x, t = threadIdx.x;
  float a = alpha[row];
  size_t base = (size_t)row * 1024 + t * 4;
  float4 v = *(const float4*)&VAL[base];
  float4 e = *(const float4*)&EO[base];
  float xv[4] = {v.x, v.y, v.z, v.w};
  float ev[4] = {e.x, e.y, e.z, e.w};
  float xo[4];
  #pragma unroll
  for (int i = 0; i < 4; ++i) {
    float xl = a * xv[i];
    float sg = 1.f / (1.f + expf(xl));
    float sw = sg * sg;
    xo[i] = xl * 2.f * sw + 2.f * ev[i] * (1.f - sw);
  }
  float4 r = {xo[0], xo[1], xo[2], xo[3]};
  *(float4*)&VAL[base] = r;
}

__global__ void ones_kernel(float* __restrict__ p, int n)
{
  int i = blockIdx.x * 256 + threadIdx.x;
  if (i < n) p[i] = 1.f;
}

__global__ __launch_bounds__(256) void pooled_kernel(
    const float* __restrict__ XO, float* __restrict__ pool)
{
  int c = blockIdx.x * 256 + threadIdx.x;
  int r0 = blockIdx.y * 500;
  float acc = 0.f;
  for (int r = r0; r < r0 + 500; ++r) acc += XO[(size_t)r * DIM + c];
  atomicAdd(&pool[c], acc);
}

__global__ __launch_bounds__(128) void final_kernel(
    const float* __restrict__ pool, const float* __restrict__ fcw,
    const float* __restrict__ fcb, const float* __restrict__ fcb2,
    float* __restrict__ out)
{
  int t = threadIdx.x, c = t >> 6, lane = t & 63;
  float acc = 0.f;
  for (int d = lane; d < DIM; d += 64)
    acc += pool[d] * (1.f / (float)NTOK) * fcw[d * 2 + c];
  acc = warpSum(acc);
  if (lane == 0) out[c] = acc + fcb[c] + fcb2[c];
}

// ---------------------------------------------------------------------------
extern "C" void kernel_launch(void* const* d_in, const int* in_sizes, int n_in,
                              void* d_out, int out_size, void* d_ws, size_t ws_size,
                              hipStream_t stream)
{
  float* out = (float*)d_out;

  // ---- workspace arena (identical sizes to round-4 passing build) ----
  constexpr size_t QKV_SZ = (size_t)NH * NPD * DH;   // 10,354,688 floats
  constexpr size_t O1_SZ  = (size_t)NTOK * 512;
  constexpr size_t EO_SZ  = (size_t)NTOK * DIM;
  float* w = (float*)d_ws;
  size_t o = 0;
  auto alloc = [&](size_t n) { float* p = w + o; o += (n + 3) & ~(size_t)3; return p; };
  float* Q    = alloc(QKV_SZ);
  float* K    = alloc(QKV_SZ);
  float* V    = alloc(QKV_SZ);
  float* O1   = alloc(O1_SZ);
  float* EO   = alloc(EO_SZ);
  float* QLM  = alloc((size_t)NH * NLM * DH);
  float* KLM  = alloc((size_t)NH * NLM * DH);
  float* A2   = alloc((size_t)NH * NLM * NLM);
  float* Z0   = alloc((size_t)NH * NLM * NLM);
  float* Z1   = alloc((size_t)NH * NLM * NLM);
  float* T1   = alloc((size_t)NH * NLM * NLM);
  float* T2   = alloc((size_t)NH * NLM * NLM);
  float* T3   = alloc((size_t)NH * NLM * NLM);
  float* AV   = alloc((size_t)NH * NLM * DH);
  float* WM   = alloc((size_t)NH * NLM * DH);
  float* ALPHA= alloc(NTOK);
  float* POOL = alloc(1024);
  float* SCAL = alloc(8);
  float* PMAX = alloc((size_t)4 * NCHK * NLM);
  float* MXB  = alloc((size_t)NH * NLM);
  float* AVACC= alloc((size_t)NH * NLM * DH);
  float* LSACC= alloc((size_t)NH * NLM);
  const size_t needed_bytes = o * sizeof(float);

  // Aliases (lifetimes audited):
  float* ST  = O1;          // 4*NPD*NLM <= O1+EO window; used st_gemm..pv only
  float* VAL = V;           // after conv_res (V dead) + EO gemm (O1 dead)
  float* Q2  = Q;           // after a1_fused
  float* K2  = K;           // after st_gemm/pv
  // fp16-split transposed weights live in dead small-matrix regions:
  u16* qkvT_h = (u16*)A2;                                   // 1536x1024, A2+Z0+Z1; dead before a2_kernel
  u16* qkvT_l = qkvT_h + (size_t)1536 * 1024;
  u16* outT_h = (u16*)T1;                                   // 1024x512, = T1; post-pinv
  u16* outT_l = outT_h + (size_t)1024 * 512;
  u16* wqT_h  = (u16*)T2;                                   // 4 x 256x1024 = T2
  u16* wqT_l  = wqT_h + (size_t)256 * 1024;
  u16* wkT_h  = wqT_l + (size_t)256 * 1024;
  u16* wkT_l  = wkT_h + (size_t)256 * 1024;
  u16* wvT_h  = (u16*)Z0;                                   // 1024x1024 = Z0; post-WM
  u16* wvT_l  = (u16*)Z1;

  if (n_in < 23 || ws_size < needed_bytes || out_size < 2 + NTOK + NTOK) {
    int grid = out_size > 0 ? (out_size + 255) / 256 : 1;
    zero_kernel<<<grid, 256, 0, stream>>>(out, out_size);
    return;
  }

  const float* bag  = (const float*)d_in[0];
  const float* adjv = (const float*)d_in[1];
  const float* qkvw = (const float*)d_in[2];
  const float* outw = (const float*)d_in[3];
  const float* outb = (const float*)d_in[4];
  const float* resw = (const float*)d_in[5];
  const float* wqw  = (const float*)d_in[6];
  const float* wqb  = (const float*)d_in[7];
  const float* wkw  = (const float*)d_in[8];
  const float* wkb  = (const float*)d_in[9];
  const float* wvw  = (const float*)d_in[10];
  const float* wvb  = (const float*)d_in[11];
  // d_in[12..17]: va/ua/wa — dead (k_alpha = softmax over singleton axis = 1.0)
  const float* fcw  = (const float*)d_in[18];
  const float* fcb  = (const float*)d_in[19];
  const float* fcb2 = (const float*)d_in[20];
  const int* arows  = (const int*)d_in[21];
  const int* acols  = (const int*)d_in[22];

  float* A_raw  = out + 2;
  float* kalpha = A_raw + NTOK;

  zero_kernel<<<(NTOK + 255) / 256, 256, 0, stream>>>(A_raw, NTOK);
  zero_kernel<<<4, 256, 0, stream>>>(POOL, 1024);
  zero_kernel<<<1, 256, 0, stream>>>(SCAL, 8);
  zero_kernel<<<(131072 + 255) / 256, 256, 0, stream>>>(AVACC, 131072);
  zero_kernel<<<8, 256, 0, stream>>>(LSACC, 2048);

  // --- Nystrom encoder: QKV via fp16x2 MFMA ---
  tsplit_kernel<<<dim3(1536/32, 1024/32), 256, 0, stream>>>(qkvw, qkvT_h, qkvT_l, 1024, 1536);
  gemm_h2_kernel<<<dim3(1536/128, NPD/128), 256, 0, stream>>>(
      bag, PADF, NTOK, qkvT_h, qkvT_l, nullptr, nullptr, nullptr, Q, K, V, NPD, 1536, 1024);
  landmark_kernel<<<dim3(NLM, NH), 64, 0, stream>>>(Q, QLM);
  landmark_kernel<<<dim3(NLM, NH), 64, 0, stream>>>(K, KLM);
  a2_kernel<<<dim3(NLM, NH), 256, 0, stream>>>(QLM, KLM, A2);   // overwrites qkvT (dead)
  rowcolmax_kernel<<<16, 256, 0, stream>>>(A2, SCAL);
  initz_kernel<<<dim3(NLM, NH), 256, 0, stream>>>(A2, SCAL, Z0);

  auto bgemm = [&](const float* Ab, const float* Bb, float* Cb,
                   int Ms, int Ns, int Ks, float dval, int useDiag, float scale) {
    bgemm64_kernel<<<dim3(Ns/64, Ms/64, NH), 256, 0, stream>>>(Ab, Bb, Cb, Ms, Ns, Ks, dval, useDiag, scale);
  };
  float* zc = Z0; float* zn = Z1;
  for (int it = 0; it < PITERS; ++it) {
    bgemm(A2, zc, T1, NLM, NLM, NLM, 0.f,  0, 1.f);
    bgemm(T1, T1, T2, NLM, NLM, NLM, 7.f,  1, 1.f);
    bgemm(T1, T2, T3, NLM, NLM, NLM, 15.f, 1, 1.f);
    bgemm(zc, T3, zn, NLM, NLM, NLM, 13.f, 1, 0.25f);
    float* tmp = zc; zc = zn; zn = tmp;
  }

  // --- a3@v via materialized S^T (2 chunks of 4 heads) ---
  for (int hb = 0; hb < NH; hb += 4) {
    st_gemm_kernel<<<dim3(NLM/128, NPD/128, 4), 256, 0, stream>>>(K, QLM, ST, hb);
    smax1_kernel<<<dim3(NCHK, 4), 256, 0, stream>>>(ST, PMAX);
    smax2_kernel<<<4, 256, 0, stream>>>(PMAX, MXB, hb);
    pv_kernel<<<dim3(JSPL, NLM/64, 4), 256, 0, stream>>>(ST, V, MXB, AVACC, LSACC, hb);
  }
  avnorm_kernel<<<dim3(NLM, NH), 64, 0, stream>>>(AVACC, LSACC, AV);

  bgemm(zc, AV, WM, NLM, DH, NLM, 0.f, 0, 1.f);        // W = pinv(a2) @ (a3@v)
  a1_fused_kernel<<<dim3(NTOK/8, NH), 256, 0, stream>>>(Q, KLM, WM, O1);
  conv_res_kernel<<<NTOK, 512, 0, stream>>>(V, resw, O1);

  // eo = O1 @ outw + outb + bag  (fp16x2 MFMA; outwT in dead T1)
  tsplit_kernel<<<dim3(1024/32, 512/32), 256, 0, stream>>>(outw, outT_h, outT_l, 512, 1024);
  gemm_h2_kernel<<<dim3(1024/128, (NTOK+127)/128), 256, 0, stream>>>(
      O1, 0, NTOK, outT_h, outT_l, outb, bag, EO, nullptr, nullptr, nullptr, NTOK, 1024, 512);

  // --- CustomAttention + NeighborAggregator ---
  tsplit_kernel<<<dim3(256/32, 1024/32), 256, 0, stream>>>(wqw, wqT_h, wqT_l, 1024, 256);
  tsplit_kernel<<<dim3(256/32, 1024/32), 256, 0, stream>>>(wkw, wkT_h, wkT_l, 1024, 256);
  gemm_h2_kernel<<<dim3(256/128, (NTOK+127)/128), 256, 0, stream>>>(
      EO, 0, NTOK, wqT_h, wqT_l, wqb, nullptr, Q2, nullptr, nullptr, nullptr, NTOK, 256, 1024);
  gemm_h2_kernel<<<dim3(256/128, (NTOK+127)/128), 256, 0, stream>>>(
      EO, 0, NTOK, wkT_h, wkT_l, wkb, nullptr, K2, nullptr, nullptr, nullptr, NTOK, 256, 1024);
  edge_kernel<<<NEDGE/4, 256, 0, stream>>>(Q2, K2, arows, acols, adjv, A_raw);
  softmax_vec_kernel<<<1, 1024, 0, stream>>>(A_raw, ALPHA);

  // --- value / gating / pooling ---
  tsplit_kernel<<<dim3(1024/32, 1024/32), 256, 0, stream>>>(wvw, wvT_h, wvT_l, 1024, 1024);
  gemm_h2_kernel<<<dim3(1024/128, (NTOK+127)/128), 256, 0, stream>>>(
      bag, 0, NTOK, wvT_h, wvT_l, wvb, nullptr, VAL, nullptr, nullptr, nullptr, NTOK, 1024, 1024);
  xo_kernel<<<NTOK, 256, 0, stream>>>(ALPHA, VAL, EO);
  ones_kernel<<<(NTOK+255)/256, 256, 0, stream>>>(kalpha, NTOK);
  pooled_kernel<<<dim3(4, 40), 256, 0, stream>>>(VAL, POOL);
  final_kernel<<<1, 128, 0, stream>>>(POOL, fcw, fcb, fcb2, out);
}

// Round 9
// 2311.301 us; speedup vs baseline: 2.7658x; 1.1093x over previous
//
#include <hip/hip_runtime.h>
#include <math.h>

// ---------------------------------------------------------------------------
// CAMIL forward on MI355X. Round 9 = rounds 6/7/8 resubmit (all env failures):
// a1 path (QK^T->softmax->PV) as fused fp16x2 MFMA kernel (was 402us scalar).
constexpr int NTOK = 20000;   // N
constexpr int DIM  = 1024;    // D
constexpr int NEDGE= 320000;  // E
constexpr int NH   = 8;       // heads
constexpr int DH   = 64;      // head dim
constexpr int NLM  = 256;     // landmarks M
constexpr int PADF = 224;     // front pad  (M - N%M)
constexpr int NPD  = 20224;   // N + pad
constexpr int LGRP = 79;      // NPD / NLM
constexpr int PITERS = 6;
constexpr int JSPL = 16;              // pv split-K chunks
constexpr int JLEN = NPD / JSPL;      // 1264
constexpr int NCHK = 79;              // smax1 chunks (NPD / 256)

typedef unsigned short u16;
typedef _Float16 f16x8 __attribute__((ext_vector_type(8)));
typedef float    f32x4 __attribute__((ext_vector_type(4)));
typedef u16      u16x8 __attribute__((ext_vector_type(8)));
typedef u16      u16x4 __attribute__((ext_vector_type(4)));

__device__ __forceinline__ float warpSum(float v){
  #pragma unroll
  for (int o = 32; o; o >>= 1) v += __shfl_xor(v, o);
  return v;
}
__device__ __forceinline__ float warpMax(float v){
  #pragma unroll
  for (int o = 32; o; o >>= 1) v = fmaxf(v, __shfl_xor(v, o));
  return v;
}
__device__ __forceinline__ u16 f2h(float x){
  _Float16 h = (_Float16)x; return __builtin_bit_cast(u16, h);
}
__device__ __forceinline__ float h2f(u16 u){
  return (float)__builtin_bit_cast(_Float16, u);
}

__global__ void zero_kernel(float* __restrict__ p, int n)
{
  int i = blockIdx.x * 256 + threadIdx.x;
  if (i < n) p[i] = 0.f;
}

// elementwise fp32 -> fp16 hi/lo split
__global__ void split_kernel(const float* __restrict__ x,
                             u16* __restrict__ hi, u16* __restrict__ lo, int n)
{
  int i = blockIdx.x * 256 + threadIdx.x;
  if (i < n) {
    float v = x[i];
    u16 h = f2h(v);
    hi[i] = h; lo[i] = f2h(v - h2f(h));
  }
}

// WM [h][256][64] -> WT hi/lo [h][64][256] (transpose+split, per 64-kl chunk)
__global__ __launch_bounds__(256) void wsplit_kernel(
    const float* __restrict__ W, u16* __restrict__ Th, u16* __restrict__ Tl)
{
  __shared__ float tile[64][65];
  const int t = threadIdx.x, kc = blockIdx.x, h = blockIdx.y;
  const float* Wh_ = W + (size_t)h * NLM * 64 + (size_t)kc * 64 * 64;
  #pragma unroll
  for (int i = 0; i < 16; ++i) {
    int idx = t + 256 * i;
    tile[idx >> 6][idx & 63] = Wh_[idx];
  }
  __syncthreads();
  #pragma unroll
  for (int i = 0; i < 16; ++i) {
    int idx = t + 256 * i;
    int dh = idx >> 6, kl2 = idx & 63;
    float v = tile[kl2][dh];
    u16 hh = f2h(v);
    size_t o = (size_t)h * 16384 + (size_t)dh * 256 + kc * 64 + kl2;
    Th[o] = hh; Tl[o] = f2h(v - h2f(hh));
  }
}

// ---------------------------------------------------------------------------
// Transpose + fp16 hi/lo split: W[K,N] f32 -> Th,Tl[N,K] fp16-bits.
__global__ __launch_bounds__(256) void tsplit_kernel(
    const float* __restrict__ W, u16* __restrict__ Th, u16* __restrict__ Tl,
    int Kd, int Nd)
{
  __shared__ float tile[32][33];
  const int t = threadIdx.x, bx = blockIdx.x, by = blockIdx.y;
  {
    int kk = t >> 3, n4 = (t & 7) * 4;
    float4 v = *(const float4*)&W[(size_t)(by*32 + kk) * Nd + bx*32 + n4];
    tile[kk][n4+0] = v.x; tile[kk][n4+1] = v.y;
    tile[kk][n4+2] = v.z; tile[kk][n4+3] = v.w;
  }
  __syncthreads();
  int nn = t >> 3, k4 = (t & 7) * 4;
  u16x4 hv, lv;
  #pragma unroll
  for (int c = 0; c < 4; ++c) {
    float x = tile[k4 + c][nn];
    u16 h = f2h(x);
    hv[c] = h;
    lv[c] = f2h(x - h2f(h));
  }
  size_t o = (size_t)(bx*32 + nn) * Kd + by*32 + k4;
  *(u16x4*)&Th[o] = hv;
  *(u16x4*)&Tl[o] = lv;
}

// ---------------------------------------------------------------------------
// fp16x2 split-precision MFMA GEMM (validated round 5).
__global__ __launch_bounds__(256) void gemm_h2_kernel(
    const float* __restrict__ A, int ashift, int arows,
    const u16* __restrict__ BTh, const u16* __restrict__ BTl,
    const float* __restrict__ bias, const float* __restrict__ add,
    float* __restrict__ C,
    float* __restrict__ Qd, float* __restrict__ Kd2, float* __restrict__ Vd,
    int M, int N, int Kdim)
{
  __shared__ __align__(16) u16 AsH[128*32];
  __shared__ __align__(16) u16 AsL[128*32];
  __shared__ __align__(16) u16 BsH[128*32];
  __shared__ __align__(16) u16 BsL[128*32];
  const int tid = threadIdx.x, lane = tid & 63, wv = tid >> 6;
  const int wr = wv >> 1, wc = wv & 1;
  const int bm = blockIdx.y * 128, bn = blockIdx.x * 128;

  const int rowA = tid >> 1, half = tid & 1;
  const int rg = bm + rowA;
  const unsigned r_a = (unsigned)(rg - ashift);
  const bool av = r_a < (unsigned)arows;
  const float* Ap = A + (size_t)r_a * Kdim + half * 16;
  const u16* Bph = BTh + (size_t)(bn + rowA) * Kdim + half * 16;
  const u16* Bpl = BTl + (size_t)(bn + rowA) * Kdim + half * 16;
  auto swz3 = [](int r){ return (r ^ (r >> 2)) & 3; };
  const int swa = swz3(rowA);
  const int pg0 = (half*2) ^ swa, pg1 = (half*2 + 1) ^ swa;
  u16* wA_h0 = &AsH[rowA*32 + pg0*8]; u16* wA_h1 = &AsH[rowA*32 + pg1*8];
  u16* wA_l0 = &AsL[rowA*32 + pg0*8]; u16* wA_l1 = &AsL[rowA*32 + pg1*8];
  u16* wB_h0 = &BsH[rowA*32 + pg0*8]; u16* wB_h1 = &BsH[rowA*32 + pg1*8];
  u16* wB_l0 = &BsL[rowA*32 + pg0*8]; u16* wB_l1 = &BsL[rowA*32 + pg1*8];

  f32x4 acc[4][4];
  #pragma unroll
  for (int i = 0; i < 4; ++i)
    #pragma unroll
    for (int j = 0; j < 4; ++j) acc[i][j] = 0;

  const int lg = lane >> 4;
  const int l15 = lane & 15;

  for (int kt = 0; kt < Kdim; kt += 32) {
    float x[16];
    if (av) {
      float4 v0 = *(const float4*)(Ap + kt);
      float4 v1 = *(const float4*)(Ap + kt + 4);
      float4 v2 = *(const float4*)(Ap + kt + 8);
      float4 v3 = *(const float4*)(Ap + kt + 12);
      x[0]=v0.x; x[1]=v0.y; x[2]=v0.z; x[3]=v0.w;
      x[4]=v1.x; x[5]=v1.y; x[6]=v1.z; x[7]=v1.w;
      x[8]=v2.x; x[9]=v2.y; x[10]=v2.z; x[11]=v2.w;
      x[12]=v3.x; x[13]=v3.y; x[14]=v3.z; x[15]=v3.w;
    } else {
      #pragma unroll
      for (int e = 0; e < 16; ++e) x[e] = 0.f;
    }
    u16x8 ah0, ah1, al0, al1;
    #pragma unroll
    for (int e = 0; e < 8; ++e) {
      u16 h = f2h(x[e]);      ah0[e] = h; al0[e] = f2h(x[e]     - h2f(h));
      u16 h2 = f2h(x[8+e]);   ah1[e] = h2; al1[e] = f2h(x[8+e] - h2f(h2));
    }
    u16x8 bh0 = *(const u16x8*)(Bph + kt);
    u16x8 bh1 = *(const u16x8*)(Bph + kt + 8);
    u16x8 bl0 = *(const u16x8*)(Bpl + kt);
    u16x8 bl1 = *(const u16x8*)(Bpl + kt + 8);

    __syncthreads();
    *(u16x8*)wA_h0 = ah0; *(u16x8*)wA_h1 = ah1;
    *(u16x8*)wA_l0 = al0; *(u16x8*)wA_l1 = al1;
    *(u16x8*)wB_h0 = bh0; *(u16x8*)wB_h1 = bh1;
    *(u16x8*)wB_l0 = bl0; *(u16x8*)wB_l1 = bl1;
    __syncthreads();

    f16x8 bh[4], bl[4];
    #pragma unroll
    for (int j = 0; j < 4; ++j) {
      int lb = wc*64 + j*16 + l15;
      int offb = lb*32 + ((lg ^ swz3(lb)) * 8);
      bh[j] = __builtin_bit_cast(f16x8, *(const u16x8*)&BsH[offb]);
      bl[j] = __builtin_bit_cast(f16x8, *(const u16x8*)&BsL[offb]);
    }
    #pragma unroll
    for (int i = 0; i < 4; ++i) {
      int la = wr*64 + i*16 + l15;
      int offa = la*32 + ((lg ^ swz3(la)) * 8);
      f16x8 ah = __builtin_bit_cast(f16x8, *(const u16x8*)&AsH[offa]);
      f16x8 al = __builtin_bit_cast(f16x8, *(const u16x8*)&AsL[offa]);
      #pragma unroll
      for (int j = 0; j < 4; ++j) {
        acc[i][j] = __builtin_amdgcn_mfma_f32_16x16x32_f16(ah, bh[j], acc[i][j], 0, 0, 0);
        acc[i][j] = __builtin_amdgcn_mfma_f32_16x16x32_f16(ah, bl[j], acc[i][j], 0, 0, 0);
        acc[i][j] = __builtin_amdgcn_mfma_f32_16x16x32_f16(al, bh[j], acc[i][j], 0, 0, 0);
      }
    }
  }

  if (Qd) {
    #pragma unroll
    for (int i = 0; i < 4; ++i) {
      int row0 = bm + wr*64 + i*16 + (lane>>4)*4;
      #pragma unroll
      for (int j = 0; j < 4; ++j) {
        int col = bn + wc*64 + j*16 + l15;
        int which = col >> 9;
        float* dst = (which == 0) ? Qd : (which == 1) ? Kd2 : Vd;
        float sc = (which == 0) ? 0.125f : 1.f;
        int h = (col >> 6) & 7, dh = col & 63;
        #pragma unroll
        for (int r = 0; r < 4; ++r) {
          int gr = row0 + r;
          dst[((size_t)h * NPD + gr) * 64 + dh] = acc[i][j][r] * sc;
        }
      }
    }
  } else {
    #pragma unroll
    for (int i = 0; i < 4; ++i) {
      int row0 = bm + wr*64 + i*16 + (lane>>4)*4;
      #pragma unroll
      for (int j = 0; j < 4; ++j) {
        int col = bn + wc*64 + j*16 + l15;
        float bv = bias ? bias[col] : 0.f;
        #pragma unroll
        for (int r = 0; r < 4; ++r) {
          int gr = row0 + r;
          if (gr < M) {
            float v = acc[i][j][r] + bv;
            if (add) v += add[(size_t)gr * N + col];
            C[(size_t)gr * N + col] = v;
          }
        }
      }
    }
  }
}

// ---------------------------------------------------------------------------
// Fused a1 path via MFMA: per block (64 q-rows, 1 head):
//   S^T = KLM @ Q^T  (fp16x2, scores lane-local per q-row)
//   softmax per q-row (register shuffles), E = exp(S-mx)
//   O = (E @ W) / sum, W^T pre-split in global.
__global__ __launch_bounds__(256) void a1_mfma_kernel(
    const float* __restrict__ Q,
    const u16* __restrict__ KLMH, const u16* __restrict__ KLML,
    const u16* __restrict__ WTGH, const u16* __restrict__ WTGL,
    float* __restrict__ O1)
{
  const int h = blockIdx.y;
  const int rb = blockIdx.x * 64;
  const int tid = threadIdx.x, lane = tid & 63, wv = tid >> 6;
  const int l15 = lane & 15, lg = lane >> 4;

  // 102400B pool; phase01: KH[256][72]@0, KL@18432, QH[64][72]@36864, QL@41472
  //               phase3 : WTH[64][264]@0, WTL@16896, PH[64][136]@33792, PL@42496
  __shared__ __align__(16) u16 pool[51200];
  u16* KH = pool;
  u16* KL = pool + 18432;
  u16* QH = pool + 36864;
  u16* QL = pool + 41472;
  u16* WTH = pool;
  u16* WTL = pool + 16896;
  u16* PH  = pool + 33792;
  u16* PL  = pool + 42496;

  // ---- stage KLM (pre-split copy) + Q (convert) ----
  {
    const u16* sh = KLMH + ((size_t)h * 256 + tid) * 64;
    const u16* sl = KLML + ((size_t)h * 256 + tid) * 64;
    u16* dsh = KH + tid * 72;
    u16* dsl = KL + tid * 72;
    #pragma unroll
    for (int g = 0; g < 8; ++g) {
      *(u16x8*)(dsh + g*8) = *(const u16x8*)(sh + g*8);
      *(u16x8*)(dsl + g*8) = *(const u16x8*)(sl + g*8);
    }
  }
  {
    int row = tid >> 2, cb = (tid & 3) * 16;
    int qr = rb + row; if (qr > NTOK - 1) qr = NTOK - 1;
    const float* src = Q + ((size_t)h * NPD + PADF + qr) * 64 + cb;
    u16* qh_ = QH + row * 72 + cb;
    u16* ql_ = QL + row * 72 + cb;
    #pragma unroll
    for (int e = 0; e < 16; e += 4) {
      float4 v = *(const float4*)(src + e);
      float xs[4] = {v.x, v.y, v.z, v.w};
      #pragma unroll
      for (int c2 = 0; c2 < 4; ++c2) {
        u16 hh = f2h(xs[c2]);
        qh_[e + c2] = hh;
        ql_[e + c2] = f2h(xs[c2] - h2f(hh));
      }
    }
  }
  __syncthreads();

  // ---- QK^T: D[kl][q]; wave wv owns q cols wv*16..+15 ----
  f32x4 accs[16];
  #pragma unroll
  for (int i = 0; i < 16; ++i) accs[i] = 0;
  const int qrow = wv * 16 + l15;
  #pragma unroll
  for (int ks = 0; ks < 2; ++ks) {
    f16x8 bh = *(const f16x8*)(QH + qrow*72 + ks*32 + lg*8);
    f16x8 bl = *(const f16x8*)(QL + qrow*72 + ks*32 + lg*8);
    #pragma unroll
    for (int i = 0; i < 16; ++i) {
      const int m = i*16 + l15;
      f16x8 ah = *(const f16x8*)(KH + m*72 + ks*32 + lg*8);
      f16x8 al = *(const f16x8*)(KL + m*72 + ks*32 + lg*8);
      accs[i] = __builtin_amdgcn_mfma_f32_16x16x32_f16(ah, bh, accs[i], 0, 0, 0);
      accs[i] = __builtin_amdgcn_mfma_f32_16x16x32_f16(ah, bl, accs[i], 0, 0, 0);
      accs[i] = __builtin_amdgcn_mfma_f32_16x16x32_f16(al, bh, accs[i], 0, 0, 0);
    }
  }

  // ---- softmax over kl (lane-local 64 vals + shfl across lg) ----
  float mx = -INFINITY;
  #pragma unroll
  for (int i = 0; i < 16; ++i)
    #pragma unroll
    for (int r = 0; r < 4; ++r) mx = fmaxf(mx, accs[i][r]);
  mx = fmaxf(mx, __shfl_xor(mx, 16));
  mx = fmaxf(mx, __shfl_xor(mx, 32));
  float sm = 0.f;
  #pragma unroll
  for (int i = 0; i < 16; ++i)
    #pragma unroll
    for (int r = 0; r < 4; ++r) {
      float e = expf(accs[i][r] - mx);
      accs[i][r] = e;
      sm += e;
    }
  sm += __shfl_xor(sm, 16);
  sm += __shfl_xor(sm, 32);
  const float inv = 1.f / sm;

  __syncthreads();   // all QK LDS reads done; pool is repurposed

  // ---- stage WT (copy pre-split) ----
  {
    int dh = tid >> 2, qt = tid & 3;
    const u16* sh = WTGH + (size_t)h * 16384 + (size_t)dh * 256 + qt * 64;
    const u16* sl = WTGL + (size_t)h * 16384 + (size_t)dh * 256 + qt * 64;
    u16* dsh = WTH + dh * 264 + qt * 64;
    u16* dsl = WTL + dh * 264 + qt * 64;
    #pragma unroll
    for (int g = 0; g < 8; ++g) {
      *(u16x8*)(dsh + g*8) = *(const u16x8*)(sh + g*8);
      *(u16x8*)(dsl + g*8) = *(const u16x8*)(sl + g*8);
    }
  }

  // ---- PV in two kl-halves ----
  f32x4 acco[4];
  #pragma unroll
  for (int i = 0; i < 4; ++i) acco[i] = 0;
  #pragma unroll
  for (int kh = 0; kh < 2; ++kh) {
    // write E half (split hi/lo) to LDS
    #pragma unroll
    for (int ii = 0; ii < 8; ++ii) {
      int i = kh * 8 + ii;
      int klocal = ii * 16 + lg * 4;
      u16x4 hv, lv;
      #pragma unroll
      for (int r = 0; r < 4; ++r) {
        float v = accs[i][r];
        u16 hh = f2h(v);
        hv[r] = hh; lv[r] = f2h(v - h2f(hh));
      }
      *(u16x4*)(PH + qrow * 136 + klocal) = hv;
      *(u16x4*)(PL + qrow * 136 + klocal) = lv;
    }
    __syncthreads();
    #pragma unroll
    for (int ks = 0; ks < 4; ++ks) {
      f16x8 bh = *(const f16x8*)(PH + qrow*136 + ks*32 + lg*8);
      f16x8 bl = *(const f16x8*)(PL + qrow*136 + ks*32 + lg*8);
      #pragma unroll
      for (int i2 = 0; i2 < 4; ++i2) {
        int dh = i2 * 16 + l15;
        int ko = kh*128 + ks*32 + lg*8;
        f16x8 ah = *(const f16x8*)(WTH + dh*264 + ko);
        f16x8 al = *(const f16x8*)(WTL + dh*264 + ko);
        acco[i2] = __builtin_amdgcn_mfma_f32_16x16x32_f16(ah, bh, acco[i2], 0, 0, 0);
        acco[i2] = __builtin_amdgcn_mfma_f32_16x16x32_f16(ah, bl, acco[i2], 0, 0, 0);
        acco[i2] = __builtin_amdgcn_mfma_f32_16x16x32_f16(al, bh, acco[i2], 0, 0, 0);
      }
    }
    __syncthreads();
  }

  // ---- epilogue: O1[q][h*64+dh] = acc/sum ----
  const int grow = rb + qrow;
  if (grow < NTOK) {
    #pragma unroll
    for (int i2 = 0; i2 < 4; ++i2)
      #pragma unroll
      for (int r = 0; r < 4; ++r)
        O1[(size_t)grow * 512 + h*64 + i2*16 + lg*4 + r] = acco[i2][r] * inv;
  }
}

// ---------------------------------------------------------------------------
// Batched-per-head 64x64-tile GEMM, with optional (dval*I - B) fold + scale.
__global__ __launch_bounds__(256) void bgemm64_kernel(
    const float* __restrict__ A, const float* __restrict__ B, float* __restrict__ C,
    int Msub, int Nsub, int Ksub, float dval, int useDiag, float scale)
{
  const int h = blockIdx.z;
  const float* Ah = A + (size_t)h * Msub * Ksub;
  const float* Bh = B + (size_t)h * Ksub * Nsub;
  float* Ch = C + (size_t)h * Msub * Nsub;
  __shared__ float As[16][68];
  __shared__ float Bs[16][64];
  const int tid = threadIdx.x, tx = tid & 15, ty = tid >> 4;
  const int bm = blockIdx.y * 64, bn = blockIdx.x * 64;
  float acc[4][4] = {};
  for (int k0 = 0; k0 < Ksub; k0 += 16) {
    float ra[4], rb[4];
    #pragma unroll
    for (int i = 0; i < 4; ++i) {
      int e = tid + 256 * i;
      ra[i] = Ah[(size_t)(bm + (e >> 4)) * Ksub + k0 + (e & 15)];
      int brow = k0 + (e >> 6), bcol = bn + (e & 63);
      float bv = Bh[(size_t)brow * Nsub + bcol];
      if (useDiag) bv = ((brow == bcol) ? dval : 0.f) - bv;
      rb[i] = bv;
    }
    __syncthreads();
    #pragma unroll
    for (int i = 0; i < 4; ++i) {
      int e = tid + 256 * i;
      As[e & 15][e >> 4] = ra[i];
      Bs[e >> 6][e & 63] = rb[i];
    }
    __syncthreads();
    #pragma unroll
    for (int k = 0; k < 16; ++k) {
      float4 a = *(const float4*)&As[k][ty*4];
      float4 b = *(const float4*)&Bs[k][tx*4];
      float avv[4] = {a.x,a.y,a.z,a.w};
      float bvv[4] = {b.x,b.y,b.z,b.w};
      #pragma unroll
      for (int i = 0; i < 4; ++i)
        #pragma unroll
        for (int j = 0; j < 4; ++j)
          acc[i][j] += avv[i] * bvv[j];
    }
    __syncthreads();
  }
  #pragma unroll
  for (int i = 0; i < 4; ++i) {
    float4 v = {acc[i][0]*scale, acc[i][1]*scale, acc[i][2]*scale, acc[i][3]*scale};
    *(float4*)&Ch[(size_t)(bm + ty*4 + i) * Nsub + bn + tx*4] = v;
  }
}

// ---------------------------------------------------------------------------
__global__ __launch_bounds__(64) void landmark_kernel(
    const float* __restrict__ src, float* __restrict__ dst)
{
  int m = blockIdx.x, h = blockIdx.y, d = threadIdx.x;
  const float* p = src + ((size_t)h * NPD + (size_t)m * LGRP) * 64 + d;
  float acc = 0.f;
  for (int j = 0; j < LGRP; ++j) acc += p[(size_t)j * 64];
  dst[((size_t)h * NLM + m) * 64 + d] = acc / (float)LGRP;
}

// ---------------------------------------------------------------------------
__global__ __launch_bounds__(256) void a2_kernel(
    const float* __restrict__ qlm, const float* __restrict__ klm, float* __restrict__ a2)
{
  int i = blockIdx.x, h = blockIdx.y, t = threadIdx.x;
  int w = t >> 6, lane = t & 63;
  __shared__ float qs[64];
  __shared__ float wr[4], wr2[4];
  if (t < 64) qs[t] = qlm[((size_t)h * NLM + i) * 64 + t];
  __syncthreads();
  const float* kr = klm + ((size_t)h * NLM + t) * 64;
  float s = 0.f;
  #pragma unroll
  for (int d2 = 0; d2 < 64; d2 += 4) {
    float4 kv = *(const float4*)(kr + d2);
    s += qs[d2]*kv.x + qs[d2+1]*kv.y + qs[d2+2]*kv.z + qs[d2+3]*kv.w;
  }
  float mx = warpMax(s);
  if (lane == 0) wr[w] = mx;
  __syncthreads();
  mx = fmaxf(fmaxf(wr[0], wr[1]), fmaxf(wr[2], wr[3]));
  float e = expf(s - mx);
  float sm = warpSum(e);
  if (lane == 0) wr2[w] = sm;
  __syncthreads();
  sm = wr2[0] + wr2[1] + wr2[2] + wr2[3];
  a2[((size_t)h * NLM + i) * NLM + t] = e / sm;
}

// ---------------------------------------------------------------------------
__global__ __launch_bounds__(256) void rowcolmax_kernel(
    const float* __restrict__ a2, float* __restrict__ scal)
{
  int h = blockIdx.x >> 1, mode = blockIdx.x & 1, t = threadIdx.x;
  int w = t >> 6, lane = t & 63;
  float sum = 0.f;
  if (mode == 0) {
    const float* p = a2 + ((size_t)h * NLM + t) * NLM;
    for (int j = 0; j < NLM; ++j) sum += p[j];
  } else {
    const float* p = a2 + (size_t)h * NLM * NLM + t;
    for (int i = 0; i < NLM; ++i) sum += p[(size_t)i * NLM];
  }
  float mx = warpMax(sum);
  __shared__ float wr[4];
  if (lane == 0) wr[w] = mx;
  __syncthreads();
  if (t == 0) {
    float m2 = fmaxf(fmaxf(wr[0], wr[1]), fmaxf(wr[2], wr[3]));
    atomicMax((int*)&scal[mode], __float_as_int(m2));
  }
}

__global__ __launch_bounds__(256) void initz_kernel(
    const float* __restrict__ a2, const float* __restrict__ scal, float* __restrict__ z)
{
  int i = blockIdx.x, h = blockIdx.y, t = threadIdx.x;
  float inv = 1.f / (scal[0] * scal[1]);
  z[((size_t)h * NLM + i) * NLM + t] = a2[((size_t)h * NLM + t) * NLM + i] * inv;
}

// ---------------------------------------------------------------------------
// a3@v pipeline: ST[z][j][i] = K[h][j].QLM[h][i] (per 4-head chunk)
__global__ __launch_bounds__(256) void st_gemm_kernel(
    const float* __restrict__ K, const float* __restrict__ QLM,
    float* __restrict__ ST, int hbase)
{
  const int z = blockIdx.z, h = hbase + z;
  const float* A  = K   + (size_t)h * NPD * 64;
  const float* Bq = QLM + (size_t)h * NLM * 64;
  float* C = ST + (size_t)z * NPD * NLM;
  __shared__ float As[16][132];
  __shared__ float Bs[16][132];
  const int tid = threadIdx.x;
  const int tx = tid & 15, ty = tid >> 4;
  const int bm = blockIdx.y * 128, bn = blockIdx.x * 128;
  float acc[8][8] = {};
  for (int k0 = 0; k0 < 64; k0 += 16) {
    float ra[8], rb[8];
    #pragma unroll
    for (int i = 0; i < 8; ++i) {
      int e = tid + 256 * i;
      ra[i] = A[(size_t)(bm + (e >> 4)) * 64 + k0 + (e & 15)];
      rb[i] = Bq[(size_t)(bn + (e & 127)) * 64 + k0 + (e >> 7)];
    }
    __syncthreads();
    #pragma unroll
    for (int i = 0; i < 8; ++i) {
      int e = tid + 256 * i;
      As[e & 15][e >> 4]  = ra[i];
      Bs[e >> 7][e & 127] = rb[i];
    }
    __syncthreads();
    #pragma unroll
    for (int k = 0; k < 16; ++k) {
      float4 a0 = *(const float4*)&As[k][ty*4];
      float4 a1 = *(const float4*)&As[k][64 + ty*4];
      float4 b0 = *(const float4*)&Bs[k][tx*4];
      float4 b1 = *(const float4*)&Bs[k][64 + tx*4];
      float av[8] = {a0.x,a0.y,a0.z,a0.w,a1.x,a1.y,a1.z,a1.w};
      float bv[8] = {b0.x,b0.y,b0.z,b0.w,b1.x,b1.y,b1.z,b1.w};
      #pragma unroll
      for (int i = 0; i < 8; ++i)
        #pragma unroll
        for (int j = 0; j < 8; ++j)
          acc[i][j] += av[i] * bv[j];
    }
  }
  #pragma unroll
  for (int i = 0; i < 8; ++i) {
    int r = bm + ((i < 4) ? (ty*4 + i) : (64 + ty*4 + (i - 4)));
    #pragma unroll
    for (int jh = 0; jh < 2; ++jh) {
      int c0 = bn + jh*64 + tx*4;
      float4 v = {acc[i][jh*4+0], acc[i][jh*4+1], acc[i][jh*4+2], acc[i][jh*4+3]};
      *(float4*)&C[(size_t)r * NLM + c0] = v;
    }
  }
}

__global__ __launch_bounds__(256) void smax1_kernel(
    const float* __restrict__ ST, float* __restrict__ PMAX)
{
  int c = blockIdx.x, z = blockIdx.y, i = threadIdx.x;
  const float* p = ST + (size_t)z * NPD * NLM + (size_t)c * 256 * NLM + i;
  float mx = -INFINITY;
  #pragma unroll 8
  for (int jj = 0; jj < 256; ++jj) mx = fmaxf(mx, p[(size_t)jj * NLM]);
  PMAX[((size_t)z * NCHK + c) * NLM + i] = mx;
}

__global__ __launch_bounds__(256) void smax2_kernel(
    const float* __restrict__ PMAX, float* __restrict__ MXB, int hbase)
{
  int z = blockIdx.x, i = threadIdx.x;
  float mx = -INFINITY;
  for (int c = 0; c < NCHK; ++c)
    mx = fmaxf(mx, PMAX[((size_t)z * NCHK + c) * NLM + i]);
  MXB[(size_t)(hbase + z) * NLM + i] = mx;
}

__global__ __launch_bounds__(256) void pv_kernel(
    const float* __restrict__ ST, const float* __restrict__ V,
    const float* __restrict__ MXB, float* __restrict__ AVACC,
    float* __restrict__ LSACC, int hbase)
{
  const int z = blockIdx.z, h = hbase + z;
  const int i0 = blockIdx.y * 64;
  const int j0 = blockIdx.x * JLEN;
  const float* STh = ST + (size_t)z * NPD * NLM;
  const float* Vh  = V  + (size_t)h * NPD * 64;
  const int tid = threadIdx.x, tx = tid & 15, ty = tid >> 4;
  const int il = tid & 63;
  const float mloc = MXB[(size_t)h * NLM + i0 + il];
  __shared__ float As[16][68];
  __shared__ float Bs[16][64];
  __shared__ float S4[4][64];
  float acc[4][4] = {};
  float psum = 0.f;
  for (int k0 = 0; k0 < JLEN; k0 += 16) {
    float pa[4], pb[4];
    #pragma unroll
    for (int r = 0; r < 4; ++r) {
      int jj = (tid >> 6) + 4 * r;
      int j  = j0 + k0 + jj;
      pa[r] = expf(STh[(size_t)j * NLM + i0 + il] - mloc);
      pb[r] = Vh[(size_t)j * 64 + il];
      psum += pa[r];
    }
    __syncthreads();
    #pragma unroll
    for (int r = 0; r < 4; ++r) {
      int jj = (tid >> 6) + 4 * r;
      As[jj][il] = pa[r];
      Bs[jj][il] = pb[r];
    }
    __syncthreads();
    #pragma unroll
    for (int k = 0; k < 16; ++k) {
      float4 a = *(const float4*)&As[k][ty*4];
      float4 b = *(const float4*)&Bs[k][tx*4];
      float av[4] = {a.x,a.y,a.z,a.w};
      float bv[4] = {b.x,b.y,b.z,b.w};
      #pragma unroll
      for (int i = 0; i < 4; ++i)
        #pragma unroll
        for (int j = 0; j < 4; ++j)
          acc[i][j] += av[i] * bv[j];
    }
    __syncthreads();
  }
  S4[tid >> 6][il] = psum;
  __syncthreads();
  if (tid < 64)
    atomicAdd(&LSACC[(size_t)h * NLM + i0 + tid],
              S4[0][tid] + S4[1][tid] + S4[2][tid] + S4[3][tid]);
  #pragma unroll
  for (int i = 0; i < 4; ++i)
    #pragma unroll
    for (int d = 0; d < 4; ++d)
      atomicAdd(&AVACC[((size_t)h * NLM + i0 + ty*4 + i) * 64 + tx*4 + d], acc[i][d]);
}

__global__ __launch_bounds__(64) void avnorm_kernel(
    const float* __restrict__ AVACC, const float* __restrict__ LSACC,
    float* __restrict__ AV)
{
  int m = blockIdx.x, h = blockIdx.y, d = threadIdx.x;
  size_t idx = ((size_t)h * NLM + m) * 64 + d;
  AV[idx] = AVACC[idx] / LSACC[(size_t)h * NLM + m];
}

// ---------------------------------------------------------------------------
__global__ __launch_bounds__(512) void conv_res_kernel(
    const float* __restrict__ V, const float* __restrict__ rw, float* __restrict__ O1)
{
  int t = threadIdx.x;
  int h = t >> 6, d = t & 63;
  int i = PADF + blockIdx.x;
  __shared__ float wsm[264];
  if (t < 264) wsm[t] = rw[t];
  __syncthreads();
  const float* vp = V + ((size_t)h * NPD + i - 16) * 64 + d;
  float acc = 0.f;
  #pragma unroll
  for (int k = 0; k < 33; ++k) {
    int row = i - 16 + k;
    float vv = (row < NPD) ? vp[(size_t)k * 64] : 0.f;
    acc += wsm[h*33 + k] * vv;
  }
  O1[(size_t)blockIdx.x * 512 + t] += acc;
}

// ---------------------------------------------------------------------------
__global__ __launch_bounds__(256) void edge_kernel(
    const float* __restrict__ Q2, const float* __restrict__ K2,
    const int* __restrict__ rows, const int* __restrict__ cols,
    const float* __restrict__ vals, float* __restrict__ A_raw)
{
  int e = blockIdx.x * 4 + (threadIdx.x >> 6);
  int lane = threadIdx.x & 63;
  int r = rows[e], c = cols[e];
  float4 q = *(const float4*)&Q2[(size_t)r * 256 + lane * 4];
  float4 k = *(const float4*)&K2[(size_t)c * 256 + lane * 4];
  float s = q.x*k.x + q.y*k.y + q.z*k.z + q.w*k.w;
  s = warpSum(s);
  if (lane == 0) atomicAdd(&A_raw[r], s * 0.0625f * vals[e]);
}

__global__ __launch_bounds__(1024) void softmax_vec_kernel(
    const float* __restrict__ x, float* __restrict__ y)
{
  __shared__ float red[1024];
  int t = threadIdx.x;
  float mx = -INFINITY;
  for (int i = t; i < NTOK; i += 1024) mx = fmaxf(mx, x[i]);
  red[t] = mx; __syncthreads();
  for (int s = 512; s > 0; s >>= 1) { if (t < s) red[t] = fmaxf(red[t], red[t+s]); __syncthreads(); }
  mx = red[0]; __syncthreads();
  float sm = 0.f;
  for (int i = t; i < NTOK; i += 1024) sm += expf(x[i] - mx);
  red[t] = sm; __syncthreads();
  for (int s = 512; s > 0; s >>= 1) { if (t < s) red[t] += red[t+s]; __syncthreads(); }
  sm = red[0];
  float inv = 1.f / sm;
  for (int i = t; i < NTOK; i += 1024) y[i] = expf(x[i] - mx) * inv;
}

__global__ __launch_bounds__(256) void xo_kernel(
    const float* __restrict__ alpha, float* __restrict__ VAL, const float* __restrict__ EO)
{
  int row = blockIdx.x, t = threadIdx.x;
  float a = alpha[row];
  size_t base = (size_t)row * 1024 + t * 4;
  float4 v = *(const float4*)&VAL[base];
  float4 e = *(const float4*)&EO[base];
  float xv[4] = {v.x, v.y, v.z, v.w};
  float ev[4] = {e.x, e.y, e.z, e.w};
  float xo[4];
  #pragma unroll
  for (int i = 0; i < 4; ++i) {
    float xl = a * xv[i];
    float sg = 1.f / (1.f + expf(xl));
    float sw = sg * sg;
    xo[i] = xl * 2.f * sw + 2.f * ev[i] * (1.f - sw);
  }
  float4 r = {xo[0], xo[1], xo[2], xo[3]};
  *(float4*)&VAL[base] = r;
}

__global__ void ones_kernel(float* __restrict__ p, int n)
{
  int i = blockIdx.x * 256 + threadIdx.x;
  if (i < n) p[i] = 1.f;
}

__global__ __launch_bounds__(256) void pooled_kernel(
    const float* __restrict__ XO, float* __restrict__ pool)
{
  int c = blockIdx.x * 256 + threadIdx.x;
  int r0 = blockIdx.y * 500;
  float acc = 0.f;
  for (int r = r0; r < r0 + 500; ++r) acc += XO[(size_t)r * DIM + c];
  atomicAdd(&pool[c], acc);
}

__global__ __launch_bounds__(128) void final_kernel(
    const float* __restrict__ pool, const float* __restrict__ fcw,
    const float* __restrict__ fcb, const float* __restrict__ fcb2,
    float* __restrict__ out)
{
  int t = threadIdx.x, c = t >> 6, lane = t & 63;
  float acc = 0.f;
  for (int d = lane; d < DIM; d += 64)
    acc += pool[d] * (1.f / (float)NTOK) * fcw[d * 2 + c];
  acc = warpSum(acc);
  if (lane == 0) out[c] = acc + fcb[c] + fcb2[c];
}

// ---------------------------------------------------------------------------
extern "C" void kernel_launch(void* const* d_in, const int* in_sizes, int n_in,
                              void* d_out, int out_size, void* d_ws, size_t ws_size,
                              hipStream_t stream)
{
  float* out = (float*)d_out;

  constexpr size_t QKV_SZ = (size_t)NH * NPD * DH;
  constexpr size_t O1_SZ  = (size_t)NTOK * 512;
  constexpr size_t EO_SZ  = (size_t)NTOK * DIM;
  float* w = (float*)d_ws;
  size_t o = 0;
  auto alloc = [&](size_t n) { float* p = w + o; o += (n + 3) & ~(size_t)3; return p; };
  float* Q    = alloc(QKV_SZ);
  float* K    = alloc(QKV_SZ);
  float* V    = alloc(QKV_SZ);
  float* O1   = alloc(O1_SZ);
  float* EO   = alloc(EO_SZ);
  float* QLM  = alloc((size_t)NH * NLM * DH);
  float* KLM  = alloc((size_t)NH * NLM * DH);
  float* A2   = alloc((size_t)NH * NLM * NLM);
  float* Z0   = alloc((size_t)NH * NLM * NLM);
  float* Z1   = alloc((size_t)NH * NLM * NLM);
  float* T1   = alloc((size_t)NH * NLM * NLM);
  float* T2   = alloc((size_t)NH * NLM * NLM);
  float* T3   = alloc((size_t)NH * NLM * NLM);
  float* AV   = alloc((size_t)NH * NLM * DH);
  float* WM   = alloc((size_t)NH * NLM * DH);
  float* ALPHA= alloc(NTOK);
  float* POOL = alloc(1024);
  float* SCAL = alloc(8);
  float* PMAX = alloc((size_t)4 * NCHK * NLM);
  float* MXB  = alloc((size_t)NH * NLM);
  float* AVACC= alloc((size_t)NH * NLM * DH);
  float* LSACC= alloc((size_t)NH * NLM);
  float* KSPL = alloc(131072);   // KLM hi/lo fp16 (131072 halfs each)
  float* WSPL = alloc(131072);   // W^T hi/lo fp16
  const size_t needed_bytes = o * sizeof(float);

  // Aliases (lifetimes audited across rounds 4/5):
  float* ST  = O1;
  float* VAL = V;
  float* Q2  = Q;
  float* K2  = K;
  u16* KLMH = (u16*)KSPL; u16* KLML = KLMH + (size_t)NH * NLM * DH;
  u16* WTGH = (u16*)WSPL; u16* WTGL = WTGH + (size_t)NH * DH * NLM;
  u16* qkvT_h = (u16*)A2;                     // 1536x1024 spans A2+Z0+Z1 (dead pre-a2)
  u16* qkvT_l = qkvT_h + (size_t)1536 * 1024;
  u16* outT_h = (u16*)T1;
  u16* outT_l = outT_h + (size_t)1024 * 512;
  u16* wqT_h  = (u16*)T2;
  u16* wqT_l  = wqT_h + (size_t)256 * 1024;
  u16* wkT_h  = wqT_l + (size_t)256 * 1024;
  u16* wkT_l  = wkT_h + (size_t)256 * 1024;
  u16* wvT_h  = (u16*)Z0;
  u16* wvT_l  = (u16*)Z1;

  if (n_in < 23 || ws_size < needed_bytes || out_size < 2 + NTOK + NTOK) {
    int grid = out_size > 0 ? (out_size + 255) / 256 : 1;
    zero_kernel<<<grid, 256, 0, stream>>>(out, out_size);
    return;
  }

  const float* bag  = (const float*)d_in[0];
  const float* adjv = (const float*)d_in[1];
  const float* qkvw = (const float*)d_in[2];
  const float* outw = (const float*)d_in[3];
  const float* outb = (const float*)d_in[4];
  const float* resw = (const float*)d_in[5];
  const float* wqw  = (const float*)d_in[6];
  const float* wqb  = (const float*)d_in[7];
  const float* wkw  = (const float*)d_in[8];
  const float* wkb  = (const float*)d_in[9];
  const float* wvw  = (const float*)d_in[10];
  const float* wvb  = (const float*)d_in[11];
  // d_in[12..17]: va/ua/wa — dead (k_alpha = softmax over singleton axis = 1.0)
  const float* fcw  = (const float*)d_in[18];
  const float* fcb  = (const float*)d_in[19];
  const float* fcb2 = (const float*)d_in[20];
  const int* arows  = (const int*)d_in[21];
  const int* acols  = (const int*)d_in[22];

  float* A_raw  = out + 2;
  float* kalpha = A_raw + NTOK;

  zero_kernel<<<(NTOK + 255) / 256, 256, 0, stream>>>(A_raw, NTOK);
  zero_kernel<<<4, 256, 0, stream>>>(POOL, 1024);
  zero_kernel<<<1, 256, 0, stream>>>(SCAL, 8);
  zero_kernel<<<(131072 + 255) / 256, 256, 0, stream>>>(AVACC, 131072);
  zero_kernel<<<8, 256, 0, stream>>>(LSACC, 2048);

  // --- Nystrom encoder: QKV via fp16x2 MFMA ---
  tsplit_kernel<<<dim3(1536/32, 1024/32), 256, 0, stream>>>(qkvw, qkvT_h, qkvT_l, 1024, 1536);
  gemm_h2_kernel<<<dim3(1536/128, NPD/128), 256, 0, stream>>>(
      bag, PADF, NTOK, qkvT_h, qkvT_l, nullptr, nullptr, nullptr, Q, K, V, NPD, 1536, 1024);
  landmark_kernel<<<dim3(NLM, NH), 64, 0, stream>>>(Q, QLM);
  landmark_kernel<<<dim3(NLM, NH), 64, 0, stream>>>(K, KLM);
  split_kernel<<<512, 256, 0, stream>>>(KLM, KLMH, KLML, NH * NLM * DH);
  a2_kernel<<<dim3(NLM, NH), 256, 0, stream>>>(QLM, KLM, A2);   // overwrites qkvT (dead)
  rowcolmax_kernel<<<16, 256, 0, stream>>>(A2, SCAL);
  initz_kernel<<<dim3(NLM, NH), 256, 0, stream>>>(A2, SCAL, Z0);

  auto bgemm = [&](const float* Ab, const float* Bb, float* Cb,
                   int Ms, int Ns, int Ks, float dval, int useDiag, float scale) {
    bgemm64_kernel<<<dim3(Ns/64, Ms/64, NH), 256, 0, stream>>>(Ab, Bb, Cb, Ms, Ns, Ks, dval, useDiag, scale);
  };
  float* zc = Z0; float* zn = Z1;
  for (int it = 0; it < PITERS; ++it) {
    bgemm(A2, zc, T1, NLM, NLM, NLM, 0.f,  0, 1.f);
    bgemm(T1, T1, T2, NLM, NLM, NLM, 7.f,  1, 1.f);
    bgemm(T1, T2, T3, NLM, NLM, NLM, 15.f, 1, 1.f);
    bgemm(zc, T3, zn, NLM, NLM, NLM, 13.f, 1, 0.25f);
    float* tmp = zc; zc = zn; zn = tmp;
  }

  // --- a3@v via materialized S^T (2 chunks of 4 heads) ---
  for (int hb = 0; hb < NH; hb += 4) {
    st_gemm_kernel<<<dim3(NLM/128, NPD/128, 4), 256, 0, stream>>>(K, QLM, ST, hb);
    smax1_kernel<<<dim3(NCHK, 4), 256, 0, stream>>>(ST, PMAX);
    smax2_kernel<<<4, 256, 0, stream>>>(PMAX, MXB, hb);
    pv_kernel<<<dim3(JSPL, NLM/64, 4), 256, 0, stream>>>(ST, V, MXB, AVACC, LSACC, hb);
  }
  avnorm_kernel<<<dim3(NLM, NH), 64, 0, stream>>>(AVACC, LSACC, AV);

  bgemm(zc, AV, WM, NLM, DH, NLM, 0.f, 0, 1.f);        // W = pinv(a2) @ (a3@v)
  wsplit_kernel<<<dim3(4, NH), 256, 0, stream>>>(WM, WTGH, WTGL);
  a1_mfma_kernel<<<dim3((NTOK + 63) / 64, NH), 256, 0, stream>>>(
      Q, KLMH, KLML, WTGH, WTGL, O1);
  conv_res_kernel<<<NTOK, 512, 0, stream>>>(V, resw, O1);

  // eo = O1 @ outw + outb + bag
  tsplit_kernel<<<dim3(1024/32, 512/32), 256, 0, stream>>>(outw, outT_h, outT_l, 512, 1024);
  gemm_h2_kernel<<<dim3(1024/128, (NTOK+127)/128), 256, 0, stream>>>(
      O1, 0, NTOK, outT_h, outT_l, outb, bag, EO, nullptr, nullptr, nullptr, NTOK, 1024, 512);

  // --- CustomAttention + NeighborAggregator ---
  tsplit_kernel<<<dim3(256/32, 1024/32), 256, 0, stream>>>(wqw, wqT_h, wqT_l, 1024, 256);
  tsplit_kernel<<<dim3(256/32, 1024/32), 256, 0, stream>>>(wkw, wkT_h, wkT_l, 1024, 256);
  gemm_h2_kernel<<<dim3(256/128, (NTOK+127)/128), 256, 0, stream>>>(
      EO, 0, NTOK, wqT_h, wqT_l, wqb, nullptr, Q2, nullptr, nullptr, nullptr, NTOK, 256, 1024);
  gemm_h2_kernel<<<dim3(256/128, (NTOK+127)/128), 256, 0, stream>>>(
      EO, 0, NTOK, wkT_h, wkT_l, wkb, nullptr, K2, nullptr, nullptr, nullptr, NTOK, 256, 1024);
  edge_kernel<<<NEDGE/4, 256, 0, stream>>>(Q2, K2, arows, acols, adjv, A_raw);
  softmax_vec_kernel<<<1, 1024, 0, stream>>>(A_raw, ALPHA);

  // --- value / gating / pooling ---
  tsplit_kernel<<<dim3(1024/32, 1024/32), 256, 0, stream>>>(wvw, wvT_h, wvT_l, 1024, 1024);
  gemm_h2_kernel<<<dim3(1024/128, (NTOK+127)/128), 256, 0, stream>>>(
      bag, 0, NTOK, wvT_h, wvT_l, wvb, nullptr, VAL, nullptr, nullptr, nullptr, NTOK, 1024, 1024);
  xo_kernel<<<NTOK, 256, 0, stream>>>(ALPHA, VAL, EO);
  ones_kernel<<<(NTOK+255)/256, 256, 0, stream>>>(kalpha, NTOK);
  pooled_kernel<<<dim3(4, 40), 256, 0, stream>>>(VAL, POOL);
  final_kernel<<<1, 128, 0, stream>>>(POOL, fcw, fcb, fcb2, out);
}